// Round 6
// baseline (254.036 us; speedup 1.0000x reference)
//
#include <hip/hip_runtime.h>
#include <hip/hip_cooperative_groups.h>
#include <math.h>

namespace cg = cooperative_groups;

#define B_ 2
#define U_ 32
#define V_ 2048
#define IN_ 256
#define ST_ 512
#define H_ 8
#define BU_ 64
#define NR_ 512

// ws layout (float offsets)
#define WS_SLN   0u          // [B][V][IN]      1048576
#define WS_SLNT  1048576u    // [B][IN][V]      1048576
#define WS_SCALE 2097152u    // [BU][2560]      163840  (q:0 k:512 v:768 e:1024 f1:1536 f2:2048)
#define WS_T     2260992u    // [NR][IN]        131072
#define WS_CB    2392064u    // [NR]            512
#define WS_SSUMP 2392576u    // [NR][8]         4096
#define WS_CTXP  2396672u    // [8][NR][IN]     1048576
#define WS_AO    3445248u    // [BU][512]       32768
#define WS_H2    3478016u    // [BU][512]       32768
#define WS_AOP   3510784u    // [4][BU][512]    131072

__device__ __forceinline__ float wsum(float v){
  #pragma unroll
  for(int m=32;m>0;m>>=1) v += __shfl_xor(v, m, 64);
  return v;
}

#define FMA4(A, t, S) { A.x += (t)*(S).x; A.y += (t)*(S).y; A.z += (t)*(S).z; A.w += (t)*(S).w; }

// ======================= fused cooperative kernel =======================
struct P1S { float xm[2][512]; float qv[2][64]; float red[2][4][65]; float rsm[2][4]; float rqm[2][4]; };
struct P2S { float P[16][256]; float stg[32][256]; };
struct P3S { float xs[2][256]; float m2s[128]; float ps[4][128]; float invS[2]; };
struct P4S { float xr[512]; float rsm[8]; float rqm[8]; float ps[4][128]; };
union SMem {
  float tile[32][257];   // P0a
  float cds[8][256];     // P0b
  P1S p1;
  P2S p2;                // 48 KB — the max
  P3S p3;
  P4S p4;
  float ps5[4][128];     // P5
};

__global__ __launch_bounds__(512) void k_all(
    const float* __restrict__ rst, const float* __restrict__ codes, const float* __restrict__ snd,
    const float* __restrict__ ln_s_g, const float* __restrict__ ln_s_b,
    const float* __restrict__ ln_r_g, const float* __restrict__ ln_r_b,
    const float* __restrict__ Wq, const float* __restrict__ bq, const float* __restrict__ Cq,
    const float* __restrict__ Wk, const float* __restrict__ bk, const float* __restrict__ Ck,
    const float* __restrict__ Wv, const float* __restrict__ bv, const float* __restrict__ Cv,
    const float* __restrict__ We, const float* __restrict__ be, const float* __restrict__ Ce,
    const float* __restrict__ lsa,
    const float* __restrict__ ln_f_g, const float* __restrict__ ln_f_b,
    const float* __restrict__ W1, const float* __restrict__ b1, const float* __restrict__ C1,
    const float* __restrict__ W2, const float* __restrict__ b2, const float* __restrict__ C2,
    const float* __restrict__ lsf,
    float* __restrict__ ws, float* __restrict__ out){
  cg::grid_group grid = cg::this_grid();
  __shared__ SMem sm;
  const int bid = blockIdx.x;
  const int tid = threadIdx.x;
  const int lane = tid & 63;

  // ================= P0: sender LN + transpose (bid<128) | scales (bid>=128) =================
  if(bid < 128){
    const int wave = tid >> 6;
    const int rowbase = bid * 32;
    const int b = rowbase >> 11, vloc = rowbase & 2047;
    float4 gg  = *(const float4*)(ln_s_g + lane*4);
    float4 bbv = *(const float4*)(ln_s_b + lane*4);
    #pragma unroll
    for(int it=0; it<4; ++it){
      int rl = it*8 + wave;
      int r  = rowbase + rl;
      float4 x = *(const float4*)(snd + (size_t)r*IN_ + lane*4);
      float s = x.x+x.y+x.z+x.w;
      float q = x.x*x.x+x.y*x.y+x.z*x.z+x.w*x.w;
      s = wsum(s); q = wsum(q);
      float mu = s*(1.0f/256.0f);
      float rv = rsqrtf(q*(1.0f/256.0f) - mu*mu + 1e-5f);
      float4 y;
      y.x = (x.x-mu)*rv*gg.x + bbv.x;
      y.y = (x.y-mu)*rv*gg.y + bbv.y;
      y.z = (x.z-mu)*rv*gg.z + bbv.z;
      y.w = (x.w-mu)*rv*gg.w + bbv.w;
      *(float4*)(ws + WS_SLN + (size_t)r*IN_ + lane*4) = y;
      sm.tile[rl][lane*4+0] = y.x;
      sm.tile[rl][lane*4+1] = y.y;
      sm.tile[rl][lane*4+2] = y.z;
      sm.tile[rl][lane*4+3] = y.w;
    }
    __syncthreads();
    const int vh = tid & 31, ig = tid >> 5;
    #pragma unroll
    for(int it=0; it<16; ++it){
      int i = it*16 + ig;
      ws[WS_SLNT + ((size_t)b*IN_ + i)*V_ + vloc + vh] = sm.tile[vh][i];
    }
  } else {
    const int idx = bid - 128;
    const int bg = idx >> 4, cg2 = idx & 15;   // 8 bugroups x 16 colgroups(160)
    #pragma unroll
    for(int j=0;j<4;++j){
      int fi = j*512 + tid;
      sm.cds[fi>>8][fi&255] = codes[(size_t)(bg*8)*256 + fi];
    }
    __syncthreads();
    const int wave = tid >> 6;
    const int q = lane & 3, cidx = lane >> 2;
    #pragma unroll
    for(int p=0; p<2; ++p){
      const int coll = p*128 + wave*16 + cidx;
      if(coll < 160){
        const int col = cg2*160 + coll;
        const float* Cp; int loc;
        if(col < 512){ Cp = Cq; loc = col; }
        else if(col < 768){ Cp = Ck; loc = col - 512; }
        else if(col < 1024){ Cp = Cv; loc = col - 768; }
        else if(col < 1536){ Cp = Ce; loc = col - 1024; }
        else if(col < 2048){ Cp = C1; loc = col - 1536; }
        else { Cp = C2; loc = col - 2048; }
        const float4* wrow = (const float4*)(Cp + (size_t)loc*256 + q*64);
        float acc[8] = {0,0,0,0,0,0,0,0};
        #pragma unroll 4
        for(int i=0;i<16;++i){
          float4 w = wrow[i];
          #pragma unroll
          for(int k=0;k<8;++k){
            const float4 c = *(const float4*)(&sm.cds[k][q*64 + i*4]);
            acc[k] += w.x*c.x + w.y*c.y + w.z*c.z + w.w*c.w;
          }
        }
        #pragma unroll
        for(int k=0;k<8;++k){
          acc[k] += __shfl_xor(acc[k], 1, 64);
          acc[k] += __shfl_xor(acc[k], 2, 64);
        }
        ws[WS_SCALE + (size_t)(bg*8 + q)*2560 + col]     = 1.0f + acc[q];
        ws[WS_SCALE + (size_t)(bg*8 + q + 4)*2560 + col] = 1.0f + acc[q+4];
      }
    }
  }
  grid.sync();

  // ================= P1: receiver LN + q head-slice + t_k + cb (2 vblocks/block) =================
  {
    const int hb = tid >> 8, ltid = tid & 255;
    const int vb = bid*2 + hb;
    const int bu = vb >> 3, h = vb & 7;
    const int b = bu >> 5, u = bu & 31;
    const int r = (b*8 + h)*32 + u;
    const int lw = ltid >> 6;
    P1S& S1 = sm.p1;
    float2 x2 = *(const float2*)(rst + (size_t)bu*512 + ltid*2);
    float s = x2.x + x2.y, q = x2.x*x2.x + x2.y*x2.y;
    s = wsum(s); q = wsum(q);
    if(lane==0){ S1.rsm[hb][lw] = s; S1.rqm[hb][lw] = q; }
    __syncthreads();
    float S = S1.rsm[hb][0]+S1.rsm[hb][1]+S1.rsm[hb][2]+S1.rsm[hb][3];
    float Q = S1.rqm[hb][0]+S1.rqm[hb][1]+S1.rqm[hb][2]+S1.rqm[hb][3];
    float mu = S*(1.0f/512.0f);
    float rv = rsqrtf(Q*(1.0f/512.0f) - mu*mu + 1e-5f);
    const float* scal = ws + WS_SCALE + (size_t)bu*2560;
    S1.xm[hb][ltid*2]   = ((x2.x-mu)*rv*ln_r_g[ltid*2]   + ln_r_b[ltid*2])   * scal[ltid*2];
    S1.xm[hb][ltid*2+1] = ((x2.y-mu)*rv*ln_r_g[ltid*2+1] + ln_r_b[ltid*2+1]) * scal[ltid*2+1];
    __syncthreads();
    {
      const int o = ltid & 63, sp = ltid >> 6;
      const float4* wq = (const float4*)(Wq + (size_t)(h*64 + o)*512 + sp*128);
      const float* xp = &S1.xm[hb][sp*128];
      float acc = 0.f;
      #pragma unroll 8
      for(int c4=0;c4<32;++c4){
        float4 w = wq[c4];
        acc += w.x*xp[c4*4] + w.y*xp[c4*4+1] + w.z*xp[c4*4+2] + w.w*xp[c4*4+3];
      }
      S1.red[hb][sp][o] = acc;
    }
    __syncthreads();
    if(ltid < 64)
      S1.qv[hb][ltid] = S1.red[hb][0][ltid]+S1.red[hb][1][ltid]+S1.red[hb][2][ltid]+S1.red[hb][3][ltid]
                      + bq[h*64+ltid];
    __syncthreads();
    if(ltid < 64){
      float p = S1.qv[hb][ltid] * bk[h*64+ltid];
      p = wsum(p);
      if(ltid==0) ws[WS_CB + r] = p;
    }
    {
      float acc = 0.f;
      #pragma unroll 4
      for(int d=0; d<64; ++d)
        acc += S1.qv[hb][d] * Wk[(size_t)(h*64+d)*256 + ltid];
      ws[WS_T + (size_t)r*256 + ltid] = acc * scal[512 + ltid];
    }
  }
  grid.sync();

  // ================= P2: fused scores->exp->ctx (v3 structure) =================
  {
    const int rg = bid >> 3, vc = bid & 7;
    const int r0 = rg * 16;
    const int b  = rg >> 4;
    const int v0 = vc * 256;
    const int w  = __builtin_amdgcn_readfirstlane(tid >> 6);
    const int wr = w & 1, wk = w >> 1;
    const int rw8 = wr * 8;
    const int i0 = lane * 4;
    const int srow = tid >> 6;
    const int sf   = (tid & 63) * 4;
    float (*P)[256]   = sm.p2.P;
    float (*stg)[256] = sm.p2.stg;
    const float* Tm = ws + WS_T;

    float4 a0={0,0,0,0},a1={0,0,0,0},a2={0,0,0,0},a3={0,0,0,0};
    float4 a4={0,0,0,0},a5={0,0,0,0},a6={0,0,0,0},a7={0,0,0,0};
    const float* Trow = Tm + (size_t)(r0 + rw8)*256;

    // ---- phase 1: scores = T x sT ----
    const float* p1base = ws + WS_SLNT + (size_t)b*IN_*V_ + v0;
    float4 g0,g1,g2,g3;
    g0 = *(const float4*)(p1base + (size_t)(srow    )*V_ + sf);
    g1 = *(const float4*)(p1base + (size_t)(srow+ 8)*V_ + sf);
    g2 = *(const float4*)(p1base + (size_t)(srow+16)*V_ + sf);
    g3 = *(const float4*)(p1base + (size_t)(srow+24)*V_ + sf);
    for(int s=0; s<8; ++s){
      __syncthreads();
      *(float4*)&stg[srow   ][sf] = g0;
      *(float4*)&stg[srow+ 8][sf] = g1;
      *(float4*)&stg[srow+16][sf] = g2;
      *(float4*)&stg[srow+24][sf] = g3;
      if(s < 7){
        const float* nb = p1base + (size_t)(s+1)*32*V_;
        g0 = *(const float4*)(nb + (size_t)(srow    )*V_ + sf);
        g1 = *(const float4*)(nb + (size_t)(srow+ 8)*V_ + sf);
        g2 = *(const float4*)(nb + (size_t)(srow+16)*V_ + sf);
        g3 = *(const float4*)(nb + (size_t)(srow+24)*V_ + sf);
      }
      const int kgA = s*32 + wk*8;
      float4 tA[8], tB[8];
      #pragma unroll
      for(int j=0;j<8;++j) tA[j] = *(const float4*)(Trow + (size_t)j*256 + kgA);
      __syncthreads();
      #pragma unroll
      for(int j=0;j<8;++j) tB[j] = *(const float4*)(Trow + (size_t)j*256 + kgA + 4);
      {
        const int kl = wk*8;
        float4 s0 = *(const float4*)&stg[kl+0][i0];
        float4 s1 = *(const float4*)&stg[kl+1][i0];
        float4 s2 = *(const float4*)&stg[kl+2][i0];
        float4 s3 = *(const float4*)&stg[kl+3][i0];
        FMA4(a0,tA[0].x,s0) FMA4(a0,tA[0].y,s1) FMA4(a0,tA[0].z,s2) FMA4(a0,tA[0].w,s3)
        FMA4(a1,tA[1].x,s0) FMA4(a1,tA[1].y,s1) FMA4(a1,tA[1].z,s2) FMA4(a1,tA[1].w,s3)
        FMA4(a2,tA[2].x,s0) FMA4(a2,tA[2].y,s1) FMA4(a2,tA[2].z,s2) FMA4(a2,tA[2].w,s3)
        FMA4(a3,tA[3].x,s0) FMA4(a3,tA[3].y,s1) FMA4(a3,tA[3].z,s2) FMA4(a3,tA[3].w,s3)
        FMA4(a4,tA[4].x,s0) FMA4(a4,tA[4].y,s1) FMA4(a4,tA[4].z,s2) FMA4(a4,tA[4].w,s3)
        FMA4(a5,tA[5].x,s0) FMA4(a5,tA[5].y,s1) FMA4(a5,tA[5].z,s2) FMA4(a5,tA[5].w,s3)
        FMA4(a6,tA[6].x,s0) FMA4(a6,tA[6].y,s1) FMA4(a6,tA[6].z,s2) FMA4(a6,tA[6].w,s3)
        FMA4(a7,tA[7].x,s0) FMA4(a7,tA[7].y,s1) FMA4(a7,tA[7].z,s2) FMA4(a7,tA[7].w,s3)
      }
      {
        const int kl = wk*8 + 4;
        float4 s0 = *(const float4*)&stg[kl+0][i0];
        float4 s1 = *(const float4*)&stg[kl+1][i0];
        float4 s2 = *(const float4*)&stg[kl+2][i0];
        float4 s3 = *(const float4*)&stg[kl+3][i0];
        FMA4(a0,tB[0].x,s0) FMA4(a0,tB[0].y,s1) FMA4(a0,tB[0].z,s2) FMA4(a0,tB[0].w,s3)
        FMA4(a1,tB[1].x,s0) FMA4(a1,tB[1].y,s1) FMA4(a1,tB[1].z,s2) FMA4(a1,tB[1].w,s3)
        FMA4(a2,tB[2].x,s0) FMA4(a2,tB[2].y,s1) FMA4(a2,tB[2].z,s2) FMA4(a2,tB[2].w,s3)
        FMA4(a3,tB[3].x,s0) FMA4(a3,tB[3].y,s1) FMA4(a3,tB[3].z,s2) FMA4(a3,tB[3].w,s3)
        FMA4(a4,tB[4].x,s0) FMA4(a4,tB[4].y,s1) FMA4(a4,tB[4].z,s2) FMA4(a4,tB[4].w,s3)
        FMA4(a5,tB[5].x,s0) FMA4(a5,tB[5].y,s1) FMA4(a5,tB[5].z,s2) FMA4(a5,tB[5].w,s3)
        FMA4(a6,tB[6].x,s0) FMA4(a6,tB[6].y,s1) FMA4(a6,tB[6].z,s2) FMA4(a6,tB[6].w,s3)
        FMA4(a7,tB[7].x,s0) FMA4(a7,tB[7].y,s1) FMA4(a7,tB[7].z,s2) FMA4(a7,tB[7].w,s3)
      }
    }
    __syncthreads();
    if(wk == 0){
      *(float4*)&P[rw8+0][i0]=a0; *(float4*)&P[rw8+1][i0]=a1;
      *(float4*)&P[rw8+2][i0]=a2; *(float4*)&P[rw8+3][i0]=a3;
      *(float4*)&P[rw8+4][i0]=a4; *(float4*)&P[rw8+5][i0]=a5;
      *(float4*)&P[rw8+6][i0]=a6; *(float4*)&P[rw8+7][i0]=a7;
    } else if(wk == 1){
      *(float4*)&stg[rw8+0][i0]=a0; *(float4*)&stg[rw8+1][i0]=a1;
      *(float4*)&stg[rw8+2][i0]=a2; *(float4*)&stg[rw8+3][i0]=a3;
      *(float4*)&stg[rw8+4][i0]=a4; *(float4*)&stg[rw8+5][i0]=a5;
      *(float4*)&stg[rw8+6][i0]=a6; *(float4*)&stg[rw8+7][i0]=a7;
    } else if(wk == 2){
      *(float4*)&stg[16+rw8+0][i0]=a0; *(float4*)&stg[16+rw8+1][i0]=a1;
      *(float4*)&stg[16+rw8+2][i0]=a2; *(float4*)&stg[16+rw8+3][i0]=a3;
      *(float4*)&stg[16+rw8+4][i0]=a4; *(float4*)&stg[16+rw8+5][i0]=a5;
      *(float4*)&stg[16+rw8+6][i0]=a6; *(float4*)&stg[16+rw8+7][i0]=a7;
    }
    __syncthreads();
    if(wk == 3){
      float4 av[8] = {a0,a1,a2,a3,a4,a5,a6,a7};
      #pragma unroll
      for(int j=0;j<8;++j){
        const int r = r0 + rw8 + j;
        const float cb = ws[WS_CB + r];
        float4 q0 = *(const float4*)&P[rw8+j][i0];
        float4 q1 = *(const float4*)&stg[rw8+j][i0];
        float4 q2 = *(const float4*)&stg[16+rw8+j][i0];
        float4 e;
        e.x = __expf((av[j].x+q0.x+q1.x+q2.x+cb)*0.125f);
        e.y = __expf((av[j].y+q0.y+q1.y+q2.y+cb)*0.125f);
        e.z = __expf((av[j].z+q0.z+q1.z+q2.z+cb)*0.125f);
        e.w = __expf((av[j].w+q0.w+q1.w+q2.w+cb)*0.125f);
        *(float4*)&P[rw8+j][i0] = e;
        float ss = wsum(e.x+e.y+e.z+e.w);
        if(lane==0) ws[WS_SSUMP + (size_t)r*8 + vc] = ss;
      }
    }

    // ---- phase 2: ctx = P x SL ----
    a0=make_float4(0,0,0,0); a1=a0; a2=a0; a3=a0; a4=a0; a5=a0; a6=a0; a7=a0;
    const float* p2base = ws + WS_SLN + ((size_t)b*V_ + v0)*IN_;
    g0 = *(const float4*)(p2base + (size_t)(srow    )*IN_ + sf);
    g1 = *(const float4*)(p2base + (size_t)(srow+ 8)*IN_ + sf);
    g2 = *(const float4*)(p2base + (size_t)(srow+16)*IN_ + sf);
    g3 = *(const float4*)(p2base + (size_t)(srow+24)*IN_ + sf);
    for(int sv=0; sv<8; ++sv){
      __syncthreads();
      *(float4*)&stg[srow   ][sf] = g0;
      *(float4*)&stg[srow+ 8][sf] = g1;
      *(float4*)&stg[srow+16][sf] = g2;
      *(float4*)&stg[srow+24][sf] = g3;
      if(sv < 7){
        const float* nb = p2base + (size_t)(sv+1)*32*IN_;
        g0 = *(const float4*)(nb + (size_t)(srow    )*IN_ + sf);
        g1 = *(const float4*)(nb + (size_t)(srow+ 8)*IN_ + sf);
        g2 = *(const float4*)(nb + (size_t)(srow+16)*IN_ + sf);
        g3 = *(const float4*)(nb + (size_t)(srow+24)*IN_ + sf);
      }
      __syncthreads();
      #pragma unroll
      for(int half=0; half<2; ++half){
        const int vl = wk*8 + half*4, vg = sv*32 + vl;
        float4 p0_ = *(const float4*)&P[rw8+0][vg];
        float4 p1_ = *(const float4*)&P[rw8+1][vg];
        float4 p2_ = *(const float4*)&P[rw8+2][vg];
        float4 p3_ = *(const float4*)&P[rw8+3][vg];
        float4 p4_ = *(const float4*)&P[rw8+4][vg];
        float4 p5_ = *(const float4*)&P[rw8+5][vg];
        float4 p6_ = *(const float4*)&P[rw8+6][vg];
        float4 p7_ = *(const float4*)&P[rw8+7][vg];
        float4 s0 = *(const float4*)&stg[vl+0][i0];
        float4 s1 = *(const float4*)&stg[vl+1][i0];
        float4 s2 = *(const float4*)&stg[vl+2][i0];
        float4 s3 = *(const float4*)&stg[vl+3][i0];
        FMA4(a0,p0_.x,s0) FMA4(a0,p0_.y,s1) FMA4(a0,p0_.z,s2) FMA4(a0,p0_.w,s3)
        FMA4(a1,p1_.x,s0) FMA4(a1,p1_.y,s1) FMA4(a1,p1_.z,s2) FMA4(a1,p1_.w,s3)
        FMA4(a2,p2_.x,s0) FMA4(a2,p2_.y,s1) FMA4(a2,p2_.z,s2) FMA4(a2,p2_.w,s3)
        FMA4(a3,p3_.x,s0) FMA4(a3,p3_.y,s1) FMA4(a3,p3_.z,s2) FMA4(a3,p3_.w,s3)
        FMA4(a4,p4_.x,s0) FMA4(a4,p4_.y,s1) FMA4(a4,p4_.z,s2) FMA4(a4,p4_.w,s3)
        FMA4(a5,p5_.x,s0) FMA4(a5,p5_.y,s1) FMA4(a5,p5_.z,s2) FMA4(a5,p5_.w,s3)
        FMA4(a6,p6_.x,s0) FMA4(a6,p6_.y,s1) FMA4(a6,p6_.z,s2) FMA4(a6,p6_.w,s3)
        FMA4(a7,p7_.x,s0) FMA4(a7,p7_.y,s1) FMA4(a7,p7_.z,s2) FMA4(a7,p7_.w,s3)
      }
    }
    __syncthreads();
    if(wk == 0){
      *(float4*)&P[rw8+0][i0]=a0; *(float4*)&P[rw8+1][i0]=a1;
      *(float4*)&P[rw8+2][i0]=a2; *(float4*)&P[rw8+3][i0]=a3;
      *(float4*)&P[rw8+4][i0]=a4; *(float4*)&P[rw8+5][i0]=a5;
      *(float4*)&P[rw8+6][i0]=a6; *(float4*)&P[rw8+7][i0]=a7;
    } else if(wk == 1){
      *(float4*)&stg[rw8+0][i0]=a0; *(float4*)&stg[rw8+1][i0]=a1;
      *(float4*)&stg[rw8+2][i0]=a2; *(float4*)&stg[rw8+3][i0]=a3;
      *(float4*)&stg[rw8+4][i0]=a4; *(float4*)&stg[rw8+5][i0]=a5;
      *(float4*)&stg[rw8+6][i0]=a6; *(float4*)&stg[rw8+7][i0]=a7;
    } else if(wk == 2){
      *(float4*)&stg[16+rw8+0][i0]=a0; *(float4*)&stg[16+rw8+1][i0]=a1;
      *(float4*)&stg[16+rw8+2][i0]=a2; *(float4*)&stg[16+rw8+3][i0]=a3;
      *(float4*)&stg[16+rw8+4][i0]=a4; *(float4*)&stg[16+rw8+5][i0]=a5;
      *(float4*)&stg[16+rw8+6][i0]=a6; *(float4*)&stg[16+rw8+7][i0]=a7;
    }
    __syncthreads();
    if(wk == 3){
      float4 av[8] = {a0,a1,a2,a3,a4,a5,a6,a7};
      #pragma unroll
      for(int j=0;j<8;++j){
        const int r = r0 + rw8 + j;
        float4 q0 = *(const float4*)&P[rw8+j][i0];
        float4 q1 = *(const float4*)&stg[rw8+j][i0];
        float4 q2 = *(const float4*)&stg[16+rw8+j][i0];
        float4 d;
        d.x = av[j].x+q0.x+q1.x+q2.x;
        d.y = av[j].y+q0.y+q1.y+q2.y;
        d.z = av[j].z+q0.z+q1.z+q2.z;
        d.w = av[j].w+q0.w+q1.w+q2.w;
        *(float4*)(ws + WS_CTXP + ((size_t)vc*NR_ + r)*IN_ + i0) = d;
      }
    }
  }
  grid.sync();

  // ================= P3: msg + exit partials =================
  {
    const int bu = bid >> 2, st = bid & 3;
    const int b = bu >> 5, u = bu & 31;
    P3S& S3 = sm.p3;
    if(tid < 2){
      const int r = (b*8 + st*2 + tid)*32 + u;
      float v = 0.f;
      #pragma unroll
      for(int k=0;k<8;++k) v += ws[WS_SSUMP + (size_t)r*8 + k];
      S3.invS[tid] = 1.0f / v;
    }
    {
      const int hh = tid >> 8, i = tid & 255;
      const int r = (b*8 + st*2 + hh)*32 + u;
      float s = 0.f;
      #pragma unroll
      for(int vcx=0; vcx<8; ++vcx)
        s += ws[WS_CTXP + ((size_t)vcx*NR_ + r)*IN_ + i];
      S3.xs[hh][i] = s * ws[WS_SCALE + (size_t)bu*2560 + 768 + i];
    }
    __syncthreads();
    {
      const int lo = tid & 127, sp = tid >> 7;
      const int o = st*128 + lo;
      const float4* wv = (const float4*)(Wv + (size_t)o*256 + sp*64);
      const float* xp = &S3.xs[lo>>6][sp*64];
      float acc = 0.f;
      #pragma unroll
      for(int c4=0;c4<16;++c4){
        float4 w = wv[c4];
        acc += w.x*xp[c4*4]+w.y*xp[c4*4+1]+w.z*xp[c4*4+2]+w.w*xp[c4*4+3];
      }
      S3.ps[sp][lo] = acc;
    }
    __syncthreads();
    if(tid < 128){
      const int o = st*128 + tid;
      S3.m2s[tid] = ((S3.ps[0][tid]+S3.ps[1][tid]+S3.ps[2][tid]+S3.ps[3][tid]) * S3.invS[tid>>6] + bv[o])
                    * ws[WS_SCALE + (size_t)bu*2560 + 1024 + o];
    }
    __syncthreads();
    {
      const float4* we = (const float4*)(We + (size_t)tid*512 + st*128);
      float acc = 0.f;
      #pragma unroll 8
      for(int c4=0;c4<32;++c4){
        float4 w = we[c4];
        acc += w.x*S3.m2s[c4*4]+w.y*S3.m2s[c4*4+1]+w.z*S3.m2s[c4*4+2]+w.w*S3.m2s[c4*4+3];
      }
      ws[WS_AOP + ((size_t)st*BU_ + bu)*512 + tid] = acc;
    }
  }
  grid.sync();

  // ================= P4: AO reduce + FFN LN + W1 + gelu =================
  {
    const int bu = bid >> 2, ot = bid & 3;
    P4S& S4 = sm.p4;
    const float* scal = ws + WS_SCALE + (size_t)bu*2560;
    const float* aop = ws + WS_AOP;
    float ax = aop[((size_t)0*BU_+bu)*512 + tid]
             + aop[((size_t)1*BU_+bu)*512 + tid]
             + aop[((size_t)2*BU_+bu)*512 + tid]
             + aop[((size_t)3*BU_+bu)*512 + tid];
    float xv = (ax + be[tid]) * lsa[tid];
    if(ot == 0) ws[WS_AO + (size_t)bu*512 + tid] = xv;
    float s = wsum(xv), q = wsum(xv*xv);
    if(lane==0){ S4.rsm[tid>>6] = s; S4.rqm[tid>>6] = q; }
    __syncthreads();
    float S = 0.f, Q = 0.f;
    #pragma unroll
    for(int k=0;k<8;++k){ S += S4.rsm[k]; Q += S4.rqm[k]; }
    float mu = S*(1.0f/512.0f);
    float rv = rsqrtf(Q*(1.0f/512.0f) - mu*mu + 1e-5f);
    S4.xr[tid] = ((xv-mu)*rv*ln_f_g[tid] + ln_f_b[tid]) * scal[1536 + tid];
    __syncthreads();
    const int o = ot*128 + (tid & 127), sp = tid >> 7;
    const float4* w1 = (const float4*)(W1 + (size_t)o*512 + sp*128);
    const float* xp = S4.xr + sp*128;
    float acc = 0.f;
    #pragma unroll 8
    for(int c4=0;c4<32;++c4){
      float4 w = w1[c4];
      acc += w.x*xp[c4*4]+w.y*xp[c4*4+1]+w.z*xp[c4*4+2]+w.w*xp[c4*4+3];
    }
    S4.ps[sp][tid&127] = acc;
    __syncthreads();
    if(tid < 128){
      const int oo = ot*128 + tid;
      float hh = S4.ps[0][tid]+S4.ps[1][tid]+S4.ps[2][tid]+S4.ps[3][tid] + b1[oo];
      float ge = 0.5f*hh*(1.0f + erff(hh*0.70710678118654752f));
      ws[WS_H2 + (size_t)bu*512 + oo] = ge * scal[2048 + oo];
    }
  }
  grid.sync();

  // ================= P5: FFN W2 + residual -> out =================
  {
    const int bu = bid >> 2, st = bid & 3;
    const int lo = tid & 127, sp = tid >> 7;
    const int s = st*128 + lo;
    const float4* w2 = (const float4*)(W2 + (size_t)s*512 + sp*128);
    const float* hp = ws + WS_H2 + (size_t)bu*512 + sp*128;
    float acc = 0.f;
    #pragma unroll 8
    for(int c4=0;c4<32;++c4){
      float4 w = w2[c4];
      acc += w.x*hp[c4*4]+w.y*hp[c4*4+1]+w.z*hp[c4*4+2]+w.w*hp[c4*4+3];
    }
    sm.ps5[sp][lo] = acc;
    __syncthreads();
    if(tid < 128){
      const int ss = st*128 + tid;
      out[(size_t)bu*512 + ss] = ws[WS_AO + (size_t)bu*512 + ss]
        + (sm.ps5[0][tid]+sm.ps5[1][tid]+sm.ps5[2][tid]+sm.ps5[3][tid] + b2[ss]) * lsf[ss];
    }
  }
}

// ======================= fallback: round-5 kernel set =======================
__global__ __launch_bounds__(256) void k_pre(const float* __restrict__ snd,
    const float* __restrict__ g, const float* __restrict__ bb,
    const float* __restrict__ codes,
    const float* __restrict__ Cq, const float* __restrict__ Ck, const float* __restrict__ Cv,
    const float* __restrict__ Ce, const float* __restrict__ C1, const float* __restrict__ C2,
    float* __restrict__ ws){
  __shared__ float tile[32][261];
  __shared__ float cds[8][256];
  const int tid = threadIdx.x;
  if(blockIdx.x < 128){
    const int wave = tid>>6, lane = tid&63;
    const int rowbase = blockIdx.x * 32;
    const int b = rowbase >> 11, vloc = rowbase & 2047;
    float4 gg  = *(const float4*)(g  + lane*4);
    float4 bbv = *(const float4*)(bb + lane*4);
    for(int it=0; it<8; ++it){
      int rl = it*4 + wave;
      int r  = rowbase + rl;
      float4 x = *(const float4*)(snd + (size_t)r*IN_ + lane*4);
      float s = x.x+x.y+x.z+x.w;
      float q = x.x*x.x+x.y*x.y+x.z*x.z+x.w*x.w;
      s = wsum(s); q = wsum(q);
      float mu = s*(1.0f/256.0f);
      float rv = rsqrtf(q*(1.0f/256.0f) - mu*mu + 1e-5f);
      float4 y;
      y.x = (x.x-mu)*rv*gg.x + bbv.x;
      y.y = (x.y-mu)*rv*gg.y + bbv.y;
      y.z = (x.z-mu)*rv*gg.z + bbv.z;
      y.w = (x.w-mu)*rv*gg.w + bbv.w;
      *(float4*)(ws + WS_SLN + (size_t)r*IN_ + lane*4) = y;
      tile[rl][lane*4+0] = y.x;
      tile[rl][lane*4+1] = y.y;
      tile[rl][lane*4+2] = y.z;
      tile[rl][lane*4+3] = y.w;
    }
    __syncthreads();
    const int vh = tid & 31;
    const int ibase = (tid >> 5);
    for(int it=0; it<32; ++it){
      int i = it*8 + ibase;
      ws[WS_SLNT + ((size_t)b*IN_ + i)*V_ + vloc + vh] = tile[vh][i];
    }
  } else {
    const int idx = blockIdx.x - 128;
    const int cg = idx % 40, bg = idx / 40;
    #pragma unroll
    for(int j=0;j<8;++j){
      int fi = j*256 + tid;
      cds[fi>>8][fi&255] = codes[(size_t)(bg*8)*256 + fi];
    }
    __syncthreads();
    const int q = tid & 3;
    const int col = cg*64 + (tid >> 2);
    const float* Cp; int loc;
    if(col < 512){ Cp = Cq; loc = col; }
    else if(col < 768){ Cp = Ck; loc = col - 512; }
    else if(col < 1024){ Cp = Cv; loc = col - 768; }
    else if(col < 1536){ Cp = Ce; loc = col - 1024; }
    else if(col < 2048){ Cp = C1; loc = col - 1536; }
    else { Cp = C2; loc = col - 2048; }
    const float4* wrow = (const float4*)(Cp + (size_t)loc*256 + q*64);
    float acc[8] = {0,0,0,0,0,0,0,0};
    #pragma unroll 4
    for(int i=0;i<16;++i){
      float4 w = wrow[i];
      #pragma unroll
      for(int k=0;k<8;++k){
        const float4 c = *(const float4*)(&cds[k][q*64 + i*4]);
        acc[k] += w.x*c.x + w.y*c.y + w.z*c.z + w.w*c.w;
      }
    }
    #pragma unroll
    for(int k=0;k<8;++k){
      acc[k] += __shfl_xor(acc[k], 1, 64);
      acc[k] += __shfl_xor(acc[k], 2, 64);
    }
    ws[WS_SCALE + (size_t)(bg*8 + q)*2560 + col]     = 1.0f + acc[q];
    ws[WS_SCALE + (size_t)(bg*8 + q + 4)*2560 + col] = 1.0f + acc[q+4];
  }
}

__global__ __launch_bounds__(256) void k_qt(const float* __restrict__ rst,
    const float* __restrict__ lg, const float* __restrict__ lb,
    const float* __restrict__ Wq, const float* __restrict__ bq,
    const float* __restrict__ Wk, const float* __restrict__ bk,
    float* __restrict__ ws){
  const int bu = blockIdx.x >> 3, h = blockIdx.x & 7;
  const int b = bu >> 5, u = bu & 31;
  const int r = (b*8 + h)*32 + u;
  const int tid = threadIdx.x, wave = tid>>6, lane = tid&63;
  __shared__ float xm[512];
  __shared__ float qv[64];
  __shared__ float red[4][65];
  __shared__ float rsm[4], rqm[4];
  float2 x2 = *(const float2*)(rst + (size_t)bu*512 + tid*2);
  float s = x2.x + x2.y, q = x2.x*x2.x + x2.y*x2.y;
  s = wsum(s); q = wsum(q);
  if(lane==0){ rsm[wave] = s; rqm[wave] = q; }
  __syncthreads();
  float S = rsm[0]+rsm[1]+rsm[2]+rsm[3];
  float Q = rqm[0]+rqm[1]+rqm[2]+rqm[3];
  float mu = S*(1.0f/512.0f);
  float rv = rsqrtf(Q*(1.0f/512.0f) - mu*mu + 1e-5f);
  const float* scal = ws + WS_SCALE + (size_t)bu*2560;
  xm[tid*2]   = ((x2.x-mu)*rv*lg[tid*2]   + lb[tid*2])   * scal[tid*2];
  xm[tid*2+1] = ((x2.y-mu)*rv*lg[tid*2+1] + lb[tid*2+1]) * scal[tid*2+1];
  __syncthreads();
  {
    const int o = tid & 63, sp = tid >> 6;
    const float4* wq = (const float4*)(Wq + (size_t)(h*64 + o)*512 + sp*128);
    const float* xp = xm + sp*128;
    float acc = 0.f;
    #pragma unroll 8
    for(int c4=0;c4<32;++c4){
      float4 w = wq[c4];
      acc += w.x*xp[c4*4] + w.y*xp[c4*4+1] + w.z*xp[c4*4+2] + w.w*xp[c4*4+3];
    }
    red[sp][o] = acc;
  }
  __syncthreads();
  if(tid < 64)
    qv[tid] = red[0][tid]+red[1][tid]+red[2][tid]+red[3][tid] + bq[h*64+tid];
  __syncthreads();
  if(tid < 64){
    float p = qv[tid] * bk[h*64+tid];
    p = wsum(p);
    if(tid==0) ws[WS_CB + r] = p;
  }
  {
    float acc = 0.f;
    #pragma unroll 4
    for(int d=0; d<64; ++d)
      acc += qv[d] * Wk[(size_t)(h*64+d)*256 + tid];
    ws[WS_T + (size_t)r*256 + tid] = acc * scal[512 + tid];
  }
}

__global__ __launch_bounds__(512) void k_scctx(const float* __restrict__ Tm, float* __restrict__ ws){
  const int rg = blockIdx.x >> 3, vc = blockIdx.x & 7;
  const int r0 = rg * 16;
  const int b  = rg >> 4;
  const int v0 = vc * 256;
  const int tid = threadIdx.x, lane = tid & 63;
  const int w  = __builtin_amdgcn_readfirstlane(tid >> 6);
  const int wr = w & 1, wk = w >> 1;
  const int rw8 = wr * 8;
  const int i0 = lane * 4;
  const int srow = tid >> 6;
  const int sf   = (tid & 63) * 4;
  __shared__ float P[16][256];
  __shared__ float stg[32][256];
  float4 a0={0,0,0,0},a1={0,0,0,0},a2={0,0,0,0},a3={0,0,0,0};
  float4 a4={0,0,0,0},a5={0,0,0,0},a6={0,0,0,0},a7={0,0,0,0};
  const float* Trow = Tm + (size_t)(r0 + rw8)*256;
  const float* p1base = ws + WS_SLNT + (size_t)b*IN_*V_ + v0;
  float4 g0,g1,g2,g3;
  g0 = *(const float4*)(p1base + (size_t)(srow    )*V_ + sf);
  g1 = *(const float4*)(p1base + (size_t)(srow+ 8)*V_ + sf);
  g2 = *(const float4*)(p1base + (size_t)(srow+16)*V_ + sf);
  g3 = *(const float4*)(p1base + (size_t)(srow+24)*V_ + sf);
  for(int s=0; s<8; ++s){
    __syncthreads();
    *(float4*)&stg[srow   ][sf] = g0;
    *(float4*)&stg[srow+ 8][sf] = g1;
    *(float4*)&stg[srow+16][sf] = g2;
    *(float4*)&stg[srow+24][sf] = g3;
    if(s < 7){
      const float* nb = p1base + (size_t)(s+1)*32*V_;
      g0 = *(const float4*)(nb + (size_t)(srow    )*V_ + sf);
      g1 = *(const float4*)(nb + (size_t)(srow+ 8)*V_ + sf);
      g2 = *(const float4*)(nb + (size_t)(srow+16)*V_ + sf);
      g3 = *(const float4*)(nb + (size_t)(srow+24)*V_ + sf);
    }
    const int kgA = s*32 + wk*8;
    float4 tA[8], tB[8];
    #pragma unroll
    for(int j=0;j<8;++j) tA[j] = *(const float4*)(Trow + (size_t)j*256 + kgA);
    __syncthreads();
    #pragma unroll
    for(int j=0;j<8;++j) tB[j] = *(const float4*)(Trow + (size_t)j*256 + kgA + 4);
    {
      const int kl = wk*8;
      float4 s0 = *(const float4*)&stg[kl+0][i0];
      float4 s1 = *(const float4*)&stg[kl+1][i0];
      float4 s2 = *(const float4*)&stg[kl+2][i0];
      float4 s3 = *(const float4*)&stg[kl+3][i0];
      FMA4(a0,tA[0].x,s0) FMA4(a0,tA[0].y,s1) FMA4(a0,tA[0].z,s2) FMA4(a0,tA[0].w,s3)
      FMA4(a1,tA[1].x,s0) FMA4(a1,tA[1].y,s1) FMA4(a1,tA[1].z,s2) FMA4(a1,tA[1].w,s3)
      FMA4(a2,tA[2].x,s0) FMA4(a2,tA[2].y,s1) FMA4(a2,tA[2].z,s2) FMA4(a2,tA[2].w,s3)
      FMA4(a3,tA[3].x,s0) FMA4(a3,tA[3].y,s1) FMA4(a3,tA[3].z,s2) FMA4(a3,tA[3].w,s3)
      FMA4(a4,tA[4].x,s0) FMA4(a4,tA[4].y,s1) FMA4(a4,tA[4].z,s2) FMA4(a4,tA[4].w,s3)
      FMA4(a5,tA[5].x,s0) FMA4(a5,tA[5].y,s1) FMA4(a5,tA[5].z,s2) FMA4(a5,tA[5].w,s3)
      FMA4(a6,tA[6].x,s0) FMA4(a6,tA[6].y,s1) FMA4(a6,tA[6].z,s2) FMA4(a6,tA[6].w,s3)
      FMA4(a7,tA[7].x,s0) FMA4(a7,tA[7].y,s1) FMA4(a7,tA[7].z,s2) FMA4(a7,tA[7].w,s3)
    }
    {
      const int kl = wk*8 + 4;
      float4 s0 = *(const float4*)&stg[kl+0][i0];
      float4 s1 = *(const float4*)&stg[kl+1][i0];
      float4 s2 = *(const float4*)&stg[kl+2][i0];
      float4 s3 = *(const float4*)&stg[kl+3][i0];
      FMA4(a0,tB[0].x,s0) FMA4(a0,tB[0].y,s1) FMA4(a0,tB[0].z,s2) FMA4(a0,tB[0].w,s3)
      FMA4(a1,tB[1].x,s0) FMA4(a1,tB[1].y,s1) FMA4(a1,tB[1].z,s2) FMA4(a1,tB[1].w,s3)
      FMA4(a2,tB[2].x,s0) FMA4(a2,tB[2].y,s1) FMA4(a2,tB[2].z,s2) FMA4(a2,tB[2].w,s3)
      FMA4(a3,tB[3].x,s0) FMA4(a3,tB[3].y,s1) FMA4(a3,tB[3].z,s2) FMA4(a3,tB[3].w,s3)
      FMA4(a4,tB[4].x,s0) FMA4(a4,tB[4].y,s1) FMA4(a4,tB[4].z,s2) FMA4(a4,tB[4].w,s3)
      FMA4(a5,tB[5].x,s0) FMA4(a5,tB[5].y,s1) FMA4(a5,tB[5].z,s2) FMA4(a5,tB[5].w,s3)
      FMA4(a6,tB[6].x,s0) FMA4(a6,tB[6].y,s1) FMA4(a6,tB[6].z,s2) FMA4(a6,tB[6].w,s3)
      FMA4(a7,tB[7].x,s0) FMA4(a7,tB[7].y,s1) FMA4(a7,tB[7].z,s2) FMA4(a7,tB[7].w,s3)
    }
  }
  __syncthreads();
  if(wk == 0){
    *(float4*)&P[rw8+0][i0]=a0; *(float4*)&P[rw8+1][i0]=a1;
    *(float4*)&P[rw8+2][i0]=a2; *(float4*)&P[rw8+3][i0]=a3;
    *(float4*)&P[rw8+4][i0]=a4; *(float4*)&P[rw8+5][i0]=a5;
    *(float4*)&P[rw8+6][i0]=a6; *(float4*)&P[rw8+7][i0]=a7;
  } else if(wk == 1){
    *(float4*)&stg[rw8+0][i0]=a0; *(float4*)&stg[rw8+1][i0]=a1;
    *(float4*)&stg[rw8+2][i0]=a2; *(float4*)&stg[rw8+3][i0]=a3;
    *(float4*)&stg[rw8+4][i0]=a4; *(float4*)&stg[rw8+5][i0]=a5;
    *(float4*)&stg[rw8+6][i0]=a6; *(float4*)&stg[rw8+7][i0]=a7;
  } else if(wk == 2){
    *(float4*)&stg[16+rw8+0][i0]=a0; *(float4*)&stg[16+rw8+1][i0]=a1;
    *(float4*)&stg[16+rw8+2][i0]=a2; *(float4*)&stg[16+rw8+3][i0]=a3;
    *(float4*)&stg[16+rw8+4][i0]=a4; *(float4*)&stg[16+rw8+5][i0]=a5;
    *(float4*)&stg[16+rw8+6][i0]=a6; *(float4*)&stg[16+rw8+7][i0]=a7;
  }
  __syncthreads();
  if(wk == 3){
    float4 av[8] = {a0,a1,a2,a3,a4,a5,a6,a7};
    #pragma unroll
    for(int j=0;j<8;++j){
      const int r = r0 + rw8 + j;
      const float cb = ws[WS_CB + r];
      float4 q0 = *(const float4*)&P[rw8+j][i0];
      float4 q1 = *(const float4*)&stg[rw8+j][i0];
      float4 q2 = *(const float4*)&stg[16+rw8+j][i0];
      float4 e;
      e.x = __expf((av[j].x+q0.x+q1.x+q2.x+cb)*0.125f);
      e.y = __expf((av[j].y+q0.y+q1.y+q2.y+cb)*0.125f);
      e.z = __expf((av[j].z+q0.z+q1.z+q2.z+cb)*0.125f);
      e.w = __expf((av[j].w+q0.w+q1.w+q2.w+cb)*0.125f);
      *(float4*)&P[rw8+j][i0] = e;
      float ss = wsum(e.x+e.y+e.z+e.w);
      if(lane==0) ws[WS_SSUMP + (size_t)r*8 + vc] = ss;
    }
  }
  a0=make_float4(0,0,0,0); a1=a0; a2=a0; a3=a0; a4=a0; a5=a0; a6=a0; a7=a0;
  const float* p2base = ws + WS_SLN + ((size_t)b*V_ + v0)*IN_;
  g0 = *(const float4*)(p2base + (size_t)(srow    )*IN_ + sf);
  g1 = *(const float4*)(p2base + (size_t)(srow+ 8)*IN_ + sf);
  g2 = *(const float4*)(p2base + (size_t)(srow+16)*IN_ + sf);
  g3 = *(const float4*)(p2base + (size_t)(srow+24)*IN_ + sf);
  for(int sv=0; sv<8; ++sv){
    __syncthreads();
    *(float4*)&stg[srow   ][sf] = g0;
    *(float4*)&stg[srow+ 8][sf] = g1;
    *(float4*)&stg[srow+16][sf] = g2;
    *(float4*)&stg[srow+24][sf] = g3;
    if(sv < 7){
      const float* nb = p2base + (size_t)(sv+1)*32*IN_;
      g0 = *(const float4*)(nb + (size_t)(srow    )*IN_ + sf);
      g1 = *(const float4*)(nb + (size_t)(srow+ 8)*IN_ + sf);
      g2 = *(const float4*)(nb + (size_t)(srow+16)*IN_ + sf);
      g3 = *(const float4*)(nb + (size_t)(srow+24)*IN_ + sf);
    }
    __syncthreads();
    #pragma unroll
    for(int half=0; half<2; ++half){
      const int vl = wk*8 + half*4, vg = sv*32 + vl;
      float4 p0_ = *(const float4*)&P[rw8+0][vg];
      float4 p1_ = *(const float4*)&P[rw8+1][vg];
      float4 p2_ = *(const float4*)&P[rw8+2][vg];
      float4 p3_ = *(const float4*)&P[rw8+3][vg];
      float4 p4_ = *(const float4*)&P[rw8+4][vg];
      float4 p5_ = *(const float4*)&P[rw8+5][vg];
      float4 p6_ = *(const float4*)&P[rw8+6][vg];
      float4 p7_ = *(const float4*)&P[rw8+7][vg];
      float4 s0 = *(const float4*)&stg[vl+0][i0];
      float4 s1 = *(const float4*)&stg[vl+1][i0];
      float4 s2 = *(const float4*)&stg[vl+2][i0];
      float4 s3 = *(const float4*)&stg[vl+3][i0];
      FMA4(a0,p0_.x,s0) FMA4(a0,p0_.y,s1) FMA4(a0,p0_.z,s2) FMA4(a0,p0_.w,s3)
      FMA4(a1,p1_.x,s0) FMA4(a1,p1_.y,s1) FMA4(a1,p1_.z,s2) FMA4(a1,p1_.w,s3)
      FMA4(a2,p2_.x,s0) FMA4(a2,p2_.y,s1) FMA4(a2,p2_.z,s2) FMA4(a2,p2_.w,s3)
      FMA4(a3,p3_.x,s0) FMA4(a3,p3_.y,s1) FMA4(a3,p3_.z,s2) FMA4(a3,p3_.w,s3)
      FMA4(a4,p4_.x,s0) FMA4(a4,p4_.y,s1) FMA4(a4,p4_.z,s2) FMA4(a4,p4_.w,s3)
      FMA4(a5,p5_.x,s0) FMA4(a5,p5_.y,s1) FMA4(a5,p5_.z,s2) FMA4(a5,p5_.w,s3)
      FMA4(a6,p6_.x,s0) FMA4(a6,p6_.y,s1) FMA4(a6,p6_.z,s2) FMA4(a6,p6_.w,s3)
      FMA4(a7,p7_.x,s0) FMA4(a7,p7_.y,s1) FMA4(a7,p7_.z,s2) FMA4(a7,p7_.w,s3)
    }
  }
  __syncthreads();
  if(wk == 0){
    *(float4*)&P[rw8+0][i0]=a0; *(float4*)&P[rw8+1][i0]=a1;
    *(float4*)&P[rw8+2][i0]=a2; *(float4*)&P[rw8+3][i0]=a3;
    *(float4*)&P[rw8+4][i0]=a4; *(float4*)&P[rw8+5][i0]=a5;
    *(float4*)&P[rw8+6][i0]=a6; *(float4*)&P[rw8+7][i0]=a7;
  } else if(wk == 1){
    *(float4*)&stg[rw8+0][i0]=a0; *(float4*)&stg[rw8+1][i0]=a1;
    *(float4*)&stg[rw8+2][i0]=a2; *(float4*)&stg[rw8+3][i0]=a3;
    *(float4*)&stg[rw8+4][i0]=a4; *(float4*)&stg[rw8+5][i0]=a5;
    *(float4*)&stg[rw8+6][i0]=a6; *(float4*)&stg[rw8+7][i0]=a7;
  } else if(wk == 2){
    *(float4*)&stg[16+rw8+0][i0]=a0; *(float4*)&stg[16+rw8+1][i0]=a1;
    *(float4*)&stg[16+rw8+2][i0]=a2; *(float4*)&stg[16+rw8+3][i0]=a3;
    *(float4*)&stg[16+rw8+4][i0]=a4; *(float4*)&stg[16+rw8+5][i0]=a5;
    *(float4*)&stg[16+rw8+6][i0]=a6; *(float4*)&stg[16+rw8+7][i0]=a7;
  }
  __syncthreads();
  if(wk == 3){
    float4 av[8] = {a0,a1,a2,a3,a4,a5,a6,a7};
    #pragma unroll
    for(int j=0;j<8;++j){
      const int r = r0 + rw8 + j;
      float4 q0 = *(const float4*)&P[rw8+j][i0];
      float4 q1 = *(const float4*)&stg[rw8+j][i0];
      float4 q2 = *(const float4*)&stg[16+rw8+j][i0];
      float4 d;
      d.x = av[j].x+q0.x+q1.x+q2.x;
      d.y = av[j].y+q0.y+q1.y+q2.y;
      d.z = av[j].z+q0.z+q1.z+q2.z;
      d.w = av[j].w+q0.w+q1.w+q2.w;
      *(float4*)(ws + WS_CTXP + ((size_t)vc*NR_ + r)*IN_ + i0) = d;
    }
  }
}

__global__ __launch_bounds__(512) void k_mexit(const float* __restrict__ Wv, const float* __restrict__ bv,
    const float* __restrict__ We, float* __restrict__ ws){
  const int bu = blockIdx.x >> 2, st = blockIdx.x & 3;
  const int b = bu >> 5, u = bu & 31;
  const int tid = threadIdx.x;
  __shared__ float xs[2][256];
  __shared__ float m2s[128];
  __shared__ float ps[4][128];
  __shared__ float invS[2];
  if(tid < 2){
    const int r = (b*8 + st*2 + tid)*32 + u;
    float v = 0.f;
    #pragma unroll
    for(int k=0;k<8;++k) v += ws[WS_SSUMP + (size_t)r*8 + k];
    invS[tid] = 1.0f / v;
  }
  {
    const int hh = tid >> 8, i = tid & 255;
    const int r = (b*8 + st*2 + hh)*32 + u;
    float s = 0.f;
    #pragma unroll
    for(int vcx=0; vcx<8; ++vcx)
      s += ws[WS_CTXP + ((size_t)vcx*NR_ + r)*IN_ + i];
    xs[hh][i] = s * ws[WS_SCALE + (size_t)bu*2560 + 768 + i];
  }
  __syncthreads();
  {
    const int lo = tid & 127, sp = tid >> 7;
    const int o = st*128 + lo;
    const float4* wv = (const float4*)(Wv + (size_t)o*256 + sp*64);
    const float* xp = &xs[lo>>6][sp*64];
    float acc = 0.f;
    #pragma unroll
    for(int c4=0;c4<16;++c4){
      float4 w = wv[c4];
      acc += w.x*xp[c4*4]+w.y*xp[c4*4+1]+w.z*xp[c4*4+2]+w.w*xp[c4*4+3];
    }
    ps[sp][lo] = acc;
  }
  __syncthreads();
  if(tid < 128){
    const int o = st*128 + tid;
    m2s[tid] = ((ps[0][tid]+ps[1][tid]+ps[2][tid]+ps[3][tid]) * invS[tid>>6] + bv[o])
               * ws[WS_SCALE + (size_t)bu*2560 + 1024 + o];
  }
  __syncthreads();
  {
    const float4* we = (const float4*)(We + (size_t)tid*512 + st*128);
    float acc = 0.f;
    #pragma unroll 8
    for(int c4=0;c4<32;++c4){
      float4 w = we[c4];
      acc += w.x*m2s[c4*4]+w.y*m2s[c4*4+1]+w.z*m2s[c4*4+2]+w.w*m2s[c4*4+3];
    }
    ws[WS_AOP + ((size_t)st*BU_ + bu)*512 + tid] = acc;
  }
}

__global__ __launch_bounds__(256) void k_ffn1(const float* __restrict__ be, const float* __restrict__ lsa,
    const float* __restrict__ lg, const float* __restrict__ lb,
    const float* __restrict__ W1, const float* __restrict__ b1, float* __restrict__ ws){
  const int bu = blockIdx.x >> 2, ot = blockIdx.x & 3;
  const int tid = threadIdx.x, wave = tid>>6, lane = tid&63;
  __shared__ float xr[512];
  __shared__ float rsm[4], rqm[4];
  __shared__ float ps[2][128];
  const int s2 = tid*2;
  float2 x2;
  {
    const float* aop = ws + WS_AOP;
    float ax = aop[((size_t)0*BU_+bu)*512+s2] + aop[((size_t)1*BU_+bu)*512+s2]
             + aop[((size_t)2*BU_+bu)*512+s2] + aop[((size_t)3*BU_+bu)*512+s2];
    float ay = aop[((size_t)0*BU_+bu)*512+s2+1] + aop[((size_t)1*BU_+bu)*512+s2+1]
             + aop[((size_t)2*BU_+bu)*512+s2+1] + aop[((size_t)3*BU_+bu)*512+s2+1];
    x2.x = (ax + be[s2])   * lsa[s2];
    x2.y = (ay + be[s2+1]) * lsa[s2+1];
    *(float2*)(ws + WS_AO + (size_t)bu*512 + s2) = x2;
  }
  float s = x2.x+x2.y, q = x2.x*x2.x+x2.y*x2.y;
  s = wsum(s); q = wsum(q);
  if(lane==0){ rsm[wave]=s; rqm[wave]=q; }
  __syncthreads();
  float S=rsm[0]+rsm[1]+rsm[2]+rsm[3], Q=rqm[0]+rqm[1]+rqm[2]+rqm[3];
  float mu = S*(1.0f/512.0f);
  float rv = rsqrtf(Q*(1.0f/512.0f) - mu*mu + 1e-5f);
  const float* scal = ws + WS_SCALE + (size_t)bu*2560;
  xr[s2]   = ((x2.x-mu)*rv*lg[s2]   + lb[s2])   * scal[1536 + s2];
  xr[s2+1] = ((x2.y-mu)*rv*lg[s2+1] + lb[s2+1]) * scal[1536 + s2+1];
  __syncthreads();
  const int o = ot*128 + (tid & 127), sp = tid >> 7;
  const float4* w1 = (const float4*)(W1 + (size_t)o*512 + sp*256);
  const float* xp = xr + sp*256;
  float acc = 0.f;
  #pragma unroll 8
  for(int c4=0;c4<64;++c4){
    float4 w = w1[c4];
    acc += w.x*xp[c4*4]+w.y*xp[c4*4+1]+w.z*xp[c4*4+2]+w.w*xp[c4*4+3];
  }
  ps[sp][tid&127] = acc;
  __syncthreads();
  if(sp==0){
    float hh = ps[0][tid] + ps[1][tid] + b1[o];
    float ge = 0.5f*hh*(1.0f + erff(hh*0.70710678118654752f));
    ws[WS_H2 + (size_t)bu*512 + o] = ge * scal[2048 + o];
  }
}

__global__ __launch_bounds__(256) void k_ffn2(const float* __restrict__ W2, const float* __restrict__ b2,
    const float* __restrict__ lsf, const float* __restrict__ ws, float* __restrict__ out){
  const int bu = blockIdx.x >> 2, st = blockIdx.x & 3;
  const int tid = threadIdx.x;
  const int s = st*128 + (tid & 127), sp = tid >> 7;
  __shared__ float ps[2][128];
  const float4* w2 = (const float4*)(W2 + (size_t)s*512 + sp*256);
  const float* hp = ws + WS_H2 + (size_t)bu*512 + sp*256;
  float acc = 0.f;
  #pragma unroll 8
  for(int c4=0;c4<64;++c4){
    float4 w = w2[c4];
    acc += w.x*hp[c4*4]+w.y*hp[c4*4+1]+w.z*hp[c4*4+2]+w.w*hp[c4*4+3];
  }
  ps[sp][tid&127] = acc;
  __syncthreads();
  if(sp==0)
    out[(size_t)bu*512 + s] = ws[WS_AO + (size_t)bu*512 + s]
                            + (ps[0][tid]+ps[1][tid] + b2[s]) * lsf[s];
}

extern "C" void kernel_launch(void* const* d_in, const int* in_sizes, int n_in,
                              void* d_out, int out_size, void* d_ws, size_t ws_size,
                              hipStream_t stream) {
  (void)in_sizes; (void)n_in; (void)out_size; (void)ws_size;
  const float* rst   = (const float*)d_in[0];
  const float* codes = (const float*)d_in[2];
  const float* snd   = (const float*)d_in[3];
  const float* ln_s_g = (const float*)d_in[4];
  const float* ln_s_b = (const float*)d_in[5];
  const float* ln_r_g = (const float*)d_in[6];
  const float* ln_r_b = (const float*)d_in[7];
  const float* Wq = (const float*)d_in[8];
  const float* bq = (const float*)d_in[9];
  const float* Cq = (const float*)d_in[10];
  const float* Wk = (const float*)d_in[11];
  const float* bk = (const float*)d_in[12];
  const float* Ck = (const float*)d_in[13];
  const float* Wv = (const float*)d_in[14];
  const float* bv = (const float*)d_in[15];
  const float* Cv = (const float*)d_in[16];
  const float* We = (const float*)d_in[17];
  const float* be = (const float*)d_in[18];
  const float* Ce = (const float*)d_in[19];
  const float* lsa = (const float*)d_in[20];
  const float* ln_f_g = (const float*)d_in[21];
  const float* ln_f_b = (const float*)d_in[22];
  const float* W1 = (const float*)d_in[23];
  const float* b1 = (const float*)d_in[24];
  const float* C1 = (const float*)d_in[25];
  const float* W2 = (const float*)d_in[26];
  const float* b2 = (const float*)d_in[27];
  const float* C2 = (const float*)d_in[28];
  const float* lsf = (const float*)d_in[29];
  float* ws  = (float*)d_ws;
  float* out = (float*)d_out;

  void* args[] = {
    (void*)&rst, (void*)&codes, (void*)&snd,
    (void*)&ln_s_g, (void*)&ln_s_b, (void*)&ln_r_g, (void*)&ln_r_b,
    (void*)&Wq, (void*)&bq, (void*)&Cq,
    (void*)&Wk, (void*)&bk, (void*)&Ck,
    (void*)&Wv, (void*)&bv, (void*)&Cv,
    (void*)&We, (void*)&be, (void*)&Ce,
    (void*)&lsa,
    (void*)&ln_f_g, (void*)&ln_f_b,
    (void*)&W1, (void*)&b1, (void*)&C1,
    (void*)&W2, (void*)&b2, (void*)&C2,
    (void*)&lsf,
    (void*)&ws, (void*)&out
  };
  hipError_t err = hipLaunchCooperativeKernel(reinterpret_cast<void*>(k_all),
                                              dim3(256), dim3(512), args, 0, stream);
  if(err != hipSuccess){
    (void)hipGetLastError();   // clear and fall back to the validated 6-kernel path
    k_pre   <<<448, 256, 0, stream>>>(snd, ln_s_g, ln_s_b, codes, Cq, Ck, Cv, Ce, C1, C2, ws);
    k_qt    <<<512, 256, 0, stream>>>(rst, ln_r_g, ln_r_b, Wq, bq, Wk, bk, ws);
    k_scctx <<<256, 512, 0, stream>>>((const float*)(ws + WS_T), ws);
    k_mexit <<<256, 512, 0, stream>>>(Wv, bv, We, ws);
    k_ffn1  <<<256, 256, 0, stream>>>(be, lsa, ln_f_g, ln_f_b, W1, b1, ws);
    k_ffn2  <<<256, 256, 0, stream>>>(W2, b2, lsf, ws, out);
  }
}

// Round 7
// 148.954 us; speedup vs baseline: 1.7055x; 1.7055x over previous
//
#include <hip/hip_runtime.h>
#include <math.h>

#define B_ 2
#define U_ 32
#define V_ 2048
#define IN_ 256
#define ST_ 512
#define H_ 8
#define BU_ 64
#define NR_ 512

// ws layout (float offsets)
#define WS_SLN   0u          // [B][V][IN]      1048576
#define WS_SLNT  1048576u    // [B][IN][V]      1048576
#define WS_SCALE 2097152u    // [BU][2560]      163840  (q:0 k:512 v:768 e:1024 f1:1536 f2:2048)
#define WS_T     2260992u    // [NR][IN]        131072
#define WS_CB    2392064u    // [NR]            512
#define WS_SSUMP 2392576u    // [NR][8]         4096
#define WS_CTXP  2396672u    // [8][NR][IN]     1048576
#define WS_AO    3445248u    // [BU][512]       32768
#define WS_H2    3478016u    // [BU][512]       32768
#define WS_AOP   3510784u    // [4][BU][512]    131072

__device__ __forceinline__ float wsum(float v){
  #pragma unroll
  for(int m=32;m>0;m>>=1) v += __shfl_xor(v, m, 64);
  return v;
}

#define FMA4(A, t, S) { A.x += (t)*(S).x; A.y += (t)*(S).y; A.z += (t)*(S).z; A.w += (t)*(S).w; }

// ---------------- K1: fused sender-LN+transpose (blocks 0..127) and scales GEMM (blocks 128..447) ----------------
__global__ __launch_bounds__(256) void k_pre(const float* __restrict__ snd,
    const float* __restrict__ g, const float* __restrict__ bb,
    const float* __restrict__ codes,
    const float* __restrict__ Cq, const float* __restrict__ Ck, const float* __restrict__ Cv,
    const float* __restrict__ Ce, const float* __restrict__ C1, const float* __restrict__ C2,
    float* __restrict__ ws){
  __shared__ float tile[32][261];
  __shared__ float cds[8][256];
  const int tid = threadIdx.x;
  if(blockIdx.x < 128){
    const int wave = tid>>6, lane = tid&63;
    const int rowbase = blockIdx.x * 32;
    const int b = rowbase >> 11, vloc = rowbase & 2047;
    float4 gg  = *(const float4*)(g  + lane*4);
    float4 bbv = *(const float4*)(bb + lane*4);
    for(int it=0; it<8; ++it){
      int rl = it*4 + wave;
      int r  = rowbase + rl;
      float4 x = *(const float4*)(snd + (size_t)r*IN_ + lane*4);
      float s = x.x+x.y+x.z+x.w;
      float q = x.x*x.x+x.y*x.y+x.z*x.z+x.w*x.w;
      s = wsum(s); q = wsum(q);
      float mu = s*(1.0f/256.0f);
      float rv = rsqrtf(q*(1.0f/256.0f) - mu*mu + 1e-5f);
      float4 y;
      y.x = (x.x-mu)*rv*gg.x + bbv.x;
      y.y = (x.y-mu)*rv*gg.y + bbv.y;
      y.z = (x.z-mu)*rv*gg.z + bbv.z;
      y.w = (x.w-mu)*rv*gg.w + bbv.w;
      *(float4*)(ws + WS_SLN + (size_t)r*IN_ + lane*4) = y;
      tile[rl][lane*4+0] = y.x;
      tile[rl][lane*4+1] = y.y;
      tile[rl][lane*4+2] = y.z;
      tile[rl][lane*4+3] = y.w;
    }
    __syncthreads();
    const int vh = tid & 31;
    const int ibase = (tid >> 5);
    for(int it=0; it<32; ++it){
      int i = it*8 + ibase;
      ws[WS_SLNT + ((size_t)b*IN_ + i)*V_ + vloc + vh] = tile[vh][i];
    }
  } else {
    const int idx = blockIdx.x - 128;
    const int cg = idx % 40, bg = idx / 40;
    #pragma unroll
    for(int j=0;j<8;++j){
      int fi = j*256 + tid;
      cds[fi>>8][fi&255] = codes[(size_t)(bg*8)*256 + fi];
    }
    __syncthreads();
    const int q = tid & 3;
    const int col = cg*64 + (tid >> 2);
    const float* Cp; int loc;
    if(col < 512){ Cp = Cq; loc = col; }
    else if(col < 768){ Cp = Ck; loc = col - 512; }
    else if(col < 1024){ Cp = Cv; loc = col - 768; }
    else if(col < 1536){ Cp = Ce; loc = col - 1024; }
    else if(col < 2048){ Cp = C1; loc = col - 1536; }
    else { Cp = C2; loc = col - 2048; }
    const float4* wrow = (const float4*)(Cp + (size_t)loc*256 + q*64);
    float acc[8] = {0,0,0,0,0,0,0,0};
    #pragma unroll 4
    for(int i=0;i<16;++i){
      float4 w = wrow[i];
      #pragma unroll
      for(int k=0;k<8;++k){
        const float4 c = *(const float4*)(&cds[k][q*64 + i*4]);
        acc[k] += w.x*c.x + w.y*c.y + w.z*c.z + w.w*c.w;
      }
    }
    #pragma unroll
    for(int k=0;k<8;++k){
      acc[k] += __shfl_xor(acc[k], 1, 64);
      acc[k] += __shfl_xor(acc[k], 2, 64);
    }
    ws[WS_SCALE + (size_t)(bg*8 + q)*2560 + col]     = 1.0f + acc[q];
    ws[WS_SCALE + (size_t)(bg*8 + q + 4)*2560 + col] = 1.0f + acc[q+4];
  }
}

// ---------------- K2: fused {receiver-LN+q+T prologue} + scores->exp->ctx. 256 blocks x 512 thr ----------------
// block: 16 rows (one (b,h,u-half)) x 256 v. waves: wr(0..1) row-oct x wk(0..3) K-quarter.
__global__ __launch_bounds__(512) void k_scctx(
    const float* __restrict__ rst,
    const float* __restrict__ lg, const float* __restrict__ lb,
    const float* __restrict__ Wq, const float* __restrict__ bq,
    const float* __restrict__ Wk, const float* __restrict__ bk,
    float* __restrict__ ws){
  const int rg = blockIdx.x >> 3, vc = blockIdx.x & 7;
  const int r0 = rg * 16;
  const int b  = rg >> 4;
  const int h  = (rg >> 1) & 7;
  const int u0 = (rg & 1) * 16;
  const int v0 = vc * 256;
  const int tid = threadIdx.x, lane = tid & 63;
  const int w  = __builtin_amdgcn_readfirstlane(tid >> 6);
  const int wr = w & 1, wk = w >> 1;
  const int rw8 = wr * 8;
  const int i0 = lane * 4;
  const int srow = tid >> 6;
  const int sf   = (tid & 63) * 4;

  __shared__ float P[16][256];     // 16KB
  __shared__ float stg[32][256];   // 32KB

  // ========== prologue: replaces k_qt for this block's 16 rows ==========
  {
    float* xmF = &stg[0][0];       // [16][512] (8192 floats == stg capacity)
    float* qvF = &P[0][0];         // qv[u][o], stride 65 (1040 floats <= P capacity)
    // receiver LN * scale_q : 2 rows per wave
    #pragma unroll
    for(int rr=0; rr<2; ++rr){
      const int j = w*2 + rr;
      const int bu = b*32 + u0 + j;
      const float* xr = rst + (size_t)bu*512 + lane*8;
      float4 x0 = *(const float4*)(xr);
      float4 x1 = *(const float4*)(xr + 4);
      float s = x0.x+x0.y+x0.z+x0.w + x1.x+x1.y+x1.z+x1.w;
      float q = x0.x*x0.x+x0.y*x0.y+x0.z*x0.z+x0.w*x0.w
              + x1.x*x1.x+x1.y*x1.y+x1.z*x1.z+x1.w*x1.w;
      s = wsum(s); q = wsum(q);
      float mu = s*(1.0f/512.0f);
      float rv = rsqrtf(q*(1.0f/512.0f) - mu*mu + 1e-5f);
      const float* scq = ws + WS_SCALE + (size_t)bu*2560 + lane*8;
      float4 sq0 = *(const float4*)(scq);
      float4 sq1 = *(const float4*)(scq + 4);
      float4 gg0 = *(const float4*)(lg + lane*8);
      float4 gg1 = *(const float4*)(lg + lane*8 + 4);
      float4 bb0 = *(const float4*)(lb + lane*8);
      float4 bb1 = *(const float4*)(lb + lane*8 + 4);
      float* dst = xmF + (size_t)j*512 + lane*8;
      dst[0] = ((x0.x-mu)*rv*gg0.x + bb0.x) * sq0.x;
      dst[1] = ((x0.y-mu)*rv*gg0.y + bb0.y) * sq0.y;
      dst[2] = ((x0.z-mu)*rv*gg0.z + bb0.z) * sq0.z;
      dst[3] = ((x0.w-mu)*rv*gg0.w + bb0.w) * sq0.w;
      dst[4] = ((x1.x-mu)*rv*gg1.x + bb1.x) * sq1.x;
      dst[5] = ((x1.y-mu)*rv*gg1.y + bb1.y) * sq1.y;
      dst[6] = ((x1.z-mu)*rv*gg1.z + bb1.z) * sq1.z;
      dst[7] = ((x1.w-mu)*rv*gg1.w + bb1.w) * sq1.w;
    }
    __syncthreads();
    // qv[u][o] = Wq_h[o] . xm[u] + bq : thread (u = tid>>5, o2 = tid&31) does o = 2*o2, 2*o2+1
    {
      const int u = tid >> 5, o2 = tid & 31;
      const float* xp = xmF + (size_t)u*512;
      #pragma unroll
      for(int oo=0; oo<2; ++oo){
        const int o = o2*2 + oo;
        const float4* wq = (const float4*)(Wq + (size_t)(h*64 + o)*512);
        float acc = 0.f;
        #pragma unroll 8
        for(int c4=0; c4<128; ++c4){
          float4 wv4 = wq[c4];
          acc += wv4.x*xp[c4*4] + wv4.y*xp[c4*4+1] + wv4.z*xp[c4*4+2] + wv4.w*xp[c4*4+3];
        }
        qvF[u*65 + o] = acc + bq[h*64 + o];
      }
    }
    __syncthreads();
    // cb[u] = qv[u] . bk_h  (wave 0: 4 lanes per u)
    if(tid < 64){
      const int u = lane >> 2, dq = lane & 3;
      float p = 0.f;
      #pragma unroll
      for(int dd=0; dd<16; ++dd){
        const int d = dq*16 + dd;
        p += qvF[u*65 + d] * bk[h*64 + d];
      }
      p += __shfl_xor(p, 1, 64);
      p += __shfl_xor(p, 2, 64);
      if(dq == 0) ws[WS_CB + r0 + u] = p;   // duplicated identical writes across vc: benign
    }
    // T[u][i] = scale_k * (qv[u] . Wk_h[:,i]) : thread (u = tid>>5, il = tid&31), i = il*8..+7
    {
      const int u = tid >> 5, il = tid & 31;
      const int bu = b*32 + u0 + u;
      float4 acA = {0,0,0,0}, acB = {0,0,0,0};
      #pragma unroll 4
      for(int d=0; d<64; ++d){
        const float qd = qvF[u*65 + d];
        const float4* wk4 = (const float4*)(Wk + (size_t)(h*64 + d)*256 + il*8);
        float4 w0 = wk4[0], w1 = wk4[1];
        acA.x += qd*w0.x; acA.y += qd*w0.y; acA.z += qd*w0.z; acA.w += qd*w0.w;
        acB.x += qd*w1.x; acB.y += qd*w1.y; acB.z += qd*w1.z; acB.w += qd*w1.w;
      }
      const float* sk = ws + WS_SCALE + (size_t)bu*2560 + 512 + il*8;
      float4 s0 = *(const float4*)(sk), s1 = *(const float4*)(sk + 4);
      acA.x*=s0.x; acA.y*=s0.y; acA.z*=s0.z; acA.w*=s0.w;
      acB.x*=s1.x; acB.y*=s1.y; acB.z*=s1.z; acB.w*=s1.w;
      float* tdst = ws + WS_T + (size_t)(r0 + u)*256 + il*8;
      *(float4*)(tdst)     = acA;            // duplicated identical writes across vc: benign
      *(float4*)(tdst + 4) = acB;
    }
    __syncthreads();   // T/cb visible block-wide; stg/P free for reuse
  }

  float4 a0={0,0,0,0},a1={0,0,0,0},a2={0,0,0,0},a3={0,0,0,0};
  float4 a4={0,0,0,0},a5={0,0,0,0},a6={0,0,0,0},a7={0,0,0,0};
  const float* Trow = ws + WS_T + (size_t)(r0 + rw8)*256;   // wave-uniform base

  // ================= phase 1: scores = T x sT =================
  const float* p1base = ws + WS_SLNT + (size_t)b*IN_*V_ + v0;
  float4 g0,g1,g2,g3;
  g0 = *(const float4*)(p1base + (size_t)(srow    )*V_ + sf);
  g1 = *(const float4*)(p1base + (size_t)(srow+ 8)*V_ + sf);
  g2 = *(const float4*)(p1base + (size_t)(srow+16)*V_ + sf);
  g3 = *(const float4*)(p1base + (size_t)(srow+24)*V_ + sf);
  for(int s=0; s<8; ++s){
    __syncthreads();
    *(float4*)&stg[srow   ][sf] = g0;
    *(float4*)&stg[srow+ 8][sf] = g1;
    *(float4*)&stg[srow+16][sf] = g2;
    *(float4*)&stg[srow+24][sf] = g3;
    if(s < 7){
      const float* nb = p1base + (size_t)(s+1)*32*V_;
      g0 = *(const float4*)(nb + (size_t)(srow    )*V_ + sf);
      g1 = *(const float4*)(nb + (size_t)(srow+ 8)*V_ + sf);
      g2 = *(const float4*)(nb + (size_t)(srow+16)*V_ + sf);
      g3 = *(const float4*)(nb + (size_t)(srow+24)*V_ + sf);
    }
    const int kgA = s*32 + wk*8;       // uniform
    float4 tA[8], tB[8];
    #pragma unroll
    for(int j=0;j<8;++j) tA[j] = *(const float4*)(Trow + (size_t)j*256 + kgA);
    __syncthreads();
    #pragma unroll
    for(int j=0;j<8;++j) tB[j] = *(const float4*)(Trow + (size_t)j*256 + kgA + 4);
    {
      const int kl = wk*8;
      float4 s0 = *(const float4*)&stg[kl+0][i0];
      float4 s1 = *(const float4*)&stg[kl+1][i0];
      float4 s2 = *(const float4*)&stg[kl+2][i0];
      float4 s3 = *(const float4*)&stg[kl+3][i0];
      FMA4(a0,tA[0].x,s0) FMA4(a0,tA[0].y,s1) FMA4(a0,tA[0].z,s2) FMA4(a0,tA[0].w,s3)
      FMA4(a1,tA[1].x,s0) FMA4(a1,tA[1].y,s1) FMA4(a1,tA[1].z,s2) FMA4(a1,tA[1].w,s3)
      FMA4(a2,tA[2].x,s0) FMA4(a2,tA[2].y,s1) FMA4(a2,tA[2].z,s2) FMA4(a2,tA[2].w,s3)
      FMA4(a3,tA[3].x,s0) FMA4(a3,tA[3].y,s1) FMA4(a3,tA[3].z,s2) FMA4(a3,tA[3].w,s3)
      FMA4(a4,tA[4].x,s0) FMA4(a4,tA[4].y,s1) FMA4(a4,tA[4].z,s2) FMA4(a4,tA[4].w,s3)
      FMA4(a5,tA[5].x,s0) FMA4(a5,tA[5].y,s1) FMA4(a5,tA[5].z,s2) FMA4(a5,tA[5].w,s3)
      FMA4(a6,tA[6].x,s0) FMA4(a6,tA[6].y,s1) FMA4(a6,tA[6].z,s2) FMA4(a6,tA[6].w,s3)
      FMA4(a7,tA[7].x,s0) FMA4(a7,tA[7].y,s1) FMA4(a7,tA[7].z,s2) FMA4(a7,tA[7].w,s3)
    }
    {
      const int kl = wk*8 + 4;
      float4 s0 = *(const float4*)&stg[kl+0][i0];
      float4 s1 = *(const float4*)&stg[kl+1][i0];
      float4 s2 = *(const float4*)&stg[kl+2][i0];
      float4 s3 = *(const float4*)&stg[kl+3][i0];
      FMA4(a0,tB[0].x,s0) FMA4(a0,tB[0].y,s1) FMA4(a0,tB[0].z,s2) FMA4(a0,tB[0].w,s3)
      FMA4(a1,tB[1].x,s0) FMA4(a1,tB[1].y,s1) FMA4(a1,tB[1].z,s2) FMA4(a1,tB[1].w,s3)
      FMA4(a2,tB[2].x,s0) FMA4(a2,tB[2].y,s1) FMA4(a2,tB[2].z,s2) FMA4(a2,tB[2].w,s3)
      FMA4(a3,tB[3].x,s0) FMA4(a3,tB[3].y,s1) FMA4(a3,tB[3].z,s2) FMA4(a3,tB[3].w,s3)
      FMA4(a4,tB[4].x,s0) FMA4(a4,tB[4].y,s1) FMA4(a4,tB[4].z,s2) FMA4(a4,tB[4].w,s3)
      FMA4(a5,tB[5].x,s0) FMA4(a5,tB[5].y,s1) FMA4(a5,tB[5].z,s2) FMA4(a5,tB[5].w,s3)
      FMA4(a6,tB[6].x,s0) FMA4(a6,tB[6].y,s1) FMA4(a6,tB[6].z,s2) FMA4(a6,tB[6].w,s3)
      FMA4(a7,tB[7].x,s0) FMA4(a7,tB[7].y,s1) FMA4(a7,tB[7].z,s2) FMA4(a7,tB[7].w,s3)
    }
  }
  // ---- reduce 4 K-quarters: wk0->P, wk1->stg[0:16), wk2->stg[16:32), wk3 finishes ----
  __syncthreads();
  if(wk == 0){
    *(float4*)&P[rw8+0][i0]=a0; *(float4*)&P[rw8+1][i0]=a1;
    *(float4*)&P[rw8+2][i0]=a2; *(float4*)&P[rw8+3][i0]=a3;
    *(float4*)&P[rw8+4][i0]=a4; *(float4*)&P[rw8+5][i0]=a5;
    *(float4*)&P[rw8+6][i0]=a6; *(float4*)&P[rw8+7][i0]=a7;
  } else if(wk == 1){
    *(float4*)&stg[rw8+0][i0]=a0; *(float4*)&stg[rw8+1][i0]=a1;
    *(float4*)&stg[rw8+2][i0]=a2; *(float4*)&stg[rw8+3][i0]=a3;
    *(float4*)&stg[rw8+4][i0]=a4; *(float4*)&stg[rw8+5][i0]=a5;
    *(float4*)&stg[rw8+6][i0]=a6; *(float4*)&stg[rw8+7][i0]=a7;
  } else if(wk == 2){
    *(float4*)&stg[16+rw8+0][i0]=a0; *(float4*)&stg[16+rw8+1][i0]=a1;
    *(float4*)&stg[16+rw8+2][i0]=a2; *(float4*)&stg[16+rw8+3][i0]=a3;
    *(float4*)&stg[16+rw8+4][i0]=a4; *(float4*)&stg[16+rw8+5][i0]=a5;
    *(float4*)&stg[16+rw8+6][i0]=a6; *(float4*)&stg[16+rw8+7][i0]=a7;
  }
  __syncthreads();
  if(wk == 3){
    float4 av[8] = {a0,a1,a2,a3,a4,a5,a6,a7};
    #pragma unroll
    for(int j=0;j<8;++j){
      const int r = r0 + rw8 + j;
      const float cb = ws[WS_CB + r];
      float4 q0 = *(const float4*)&P[rw8+j][i0];
      float4 q1 = *(const float4*)&stg[rw8+j][i0];
      float4 q2 = *(const float4*)&stg[16+rw8+j][i0];
      float4 e;
      e.x = __expf((av[j].x+q0.x+q1.x+q2.x+cb)*0.125f);
      e.y = __expf((av[j].y+q0.y+q1.y+q2.y+cb)*0.125f);
      e.z = __expf((av[j].z+q0.z+q1.z+q2.z+cb)*0.125f);
      e.w = __expf((av[j].w+q0.w+q1.w+q2.w+cb)*0.125f);
      *(float4*)&P[rw8+j][i0] = e;
      float ss = wsum(e.x+e.y+e.z+e.w);
      if(lane==0) ws[WS_SSUMP + (size_t)r*8 + vc] = ss;
    }
  }

  // ================= phase 2: ctx = P x SL =================
  a0=make_float4(0,0,0,0); a1=a0; a2=a0; a3=a0; a4=a0; a5=a0; a6=a0; a7=a0;
  const float* p2base = ws + WS_SLN + ((size_t)b*V_ + v0)*IN_;
  g0 = *(const float4*)(p2base + (size_t)(srow    )*IN_ + sf);
  g1 = *(const float4*)(p2base + (size_t)(srow+ 8)*IN_ + sf);
  g2 = *(const float4*)(p2base + (size_t)(srow+16)*IN_ + sf);
  g3 = *(const float4*)(p2base + (size_t)(srow+24)*IN_ + sf);
  for(int sv=0; sv<8; ++sv){
    __syncthreads();
    *(float4*)&stg[srow   ][sf] = g0;
    *(float4*)&stg[srow+ 8][sf] = g1;
    *(float4*)&stg[srow+16][sf] = g2;
    *(float4*)&stg[srow+24][sf] = g3;
    if(sv < 7){
      const float* nb = p2base + (size_t)(sv+1)*32*IN_;
      g0 = *(const float4*)(nb + (size_t)(srow    )*IN_ + sf);
      g1 = *(const float4*)(nb + (size_t)(srow+ 8)*IN_ + sf);
      g2 = *(const float4*)(nb + (size_t)(srow+16)*IN_ + sf);
      g3 = *(const float4*)(nb + (size_t)(srow+24)*IN_ + sf);
    }
    __syncthreads();
    #pragma unroll
    for(int half=0; half<2; ++half){
      const int vl = wk*8 + half*4, vg = sv*32 + vl;
      float4 p0_ = *(const float4*)&P[rw8+0][vg];
      float4 p1_ = *(const float4*)&P[rw8+1][vg];
      float4 p2_ = *(const float4*)&P[rw8+2][vg];
      float4 p3_ = *(const float4*)&P[rw8+3][vg];
      float4 p4_ = *(const float4*)&P[rw8+4][vg];
      float4 p5_ = *(const float4*)&P[rw8+5][vg];
      float4 p6_ = *(const float4*)&P[rw8+6][vg];
      float4 p7_ = *(const float4*)&P[rw8+7][vg];
      float4 s0 = *(const float4*)&stg[vl+0][i0];
      float4 s1 = *(const float4*)&stg[vl+1][i0];
      float4 s2 = *(const float4*)&stg[vl+2][i0];
      float4 s3 = *(const float4*)&stg[vl+3][i0];
      FMA4(a0,p0_.x,s0) FMA4(a0,p0_.y,s1) FMA4(a0,p0_.z,s2) FMA4(a0,p0_.w,s3)
      FMA4(a1,p1_.x,s0) FMA4(a1,p1_.y,s1) FMA4(a1,p1_.z,s2) FMA4(a1,p1_.w,s3)
      FMA4(a2,p2_.x,s0) FMA4(a2,p2_.y,s1) FMA4(a2,p2_.z,s2) FMA4(a2,p2_.w,s3)
      FMA4(a3,p3_.x,s0) FMA4(a3,p3_.y,s1) FMA4(a3,p3_.z,s2) FMA4(a3,p3_.w,s3)
      FMA4(a4,p4_.x,s0) FMA4(a4,p4_.y,s1) FMA4(a4,p4_.z,s2) FMA4(a4,p4_.w,s3)
      FMA4(a5,p5_.x,s0) FMA4(a5,p5_.y,s1) FMA4(a5,p5_.z,s2) FMA4(a5,p5_.w,s3)
      FMA4(a6,p6_.x,s0) FMA4(a6,p6_.y,s1) FMA4(a6,p6_.z,s2) FMA4(a6,p6_.w,s3)
      FMA4(a7,p7_.x,s0) FMA4(a7,p7_.y,s1) FMA4(a7,p7_.z,s2) FMA4(a7,p7_.w,s3)
    }
  }
  // ---- reduce 4 v-quarters and store CTXP ----
  __syncthreads();
  if(wk == 0){
    *(float4*)&P[rw8+0][i0]=a0; *(float4*)&P[rw8+1][i0]=a1;
    *(float4*)&P[rw8+2][i0]=a2; *(float4*)&P[rw8+3][i0]=a3;
    *(float4*)&P[rw8+4][i0]=a4; *(float4*)&P[rw8+5][i0]=a5;
    *(float4*)&P[rw8+6][i0]=a6; *(float4*)&P[rw8+7][i0]=a7;
  } else if(wk == 1){
    *(float4*)&stg[rw8+0][i0]=a0; *(float4*)&stg[rw8+1][i0]=a1;
    *(float4*)&stg[rw8+2][i0]=a2; *(float4*)&stg[rw8+3][i0]=a3;
    *(float4*)&stg[rw8+4][i0]=a4; *(float4*)&stg[rw8+5][i0]=a5;
    *(float4*)&stg[rw8+6][i0]=a6; *(float4*)&stg[rw8+7][i0]=a7;
  } else if(wk == 2){
    *(float4*)&stg[16+rw8+0][i0]=a0; *(float4*)&stg[16+rw8+1][i0]=a1;
    *(float4*)&stg[16+rw8+2][i0]=a2; *(float4*)&stg[16+rw8+3][i0]=a3;
    *(float4*)&stg[16+rw8+4][i0]=a4; *(float4*)&stg[16+rw8+5][i0]=a5;
    *(float4*)&stg[16+rw8+6][i0]=a6; *(float4*)&stg[16+rw8+7][i0]=a7;
  }
  __syncthreads();
  if(wk == 3){
    float4 av[8] = {a0,a1,a2,a3,a4,a5,a6,a7};
    #pragma unroll
    for(int j=0;j<8;++j){
      const int r = r0 + rw8 + j;
      float4 q0 = *(const float4*)&P[rw8+j][i0];
      float4 q1 = *(const float4*)&stg[rw8+j][i0];
      float4 q2 = *(const float4*)&stg[16+rw8+j][i0];
      float4 d;
      d.x = av[j].x+q0.x+q1.x+q2.x;
      d.y = av[j].y+q0.y+q1.y+q2.y;
      d.z = av[j].z+q0.z+q1.z+q2.z;
      d.w = av[j].w+q0.w+q1.w+q2.w;
      *(float4*)(ws + WS_CTXP + ((size_t)vc*NR_ + r)*IN_ + i0) = d;
    }
  }
}

// ---------------- K3: msg+exit, column-split We -> AO partials (256 blocks = bu x st, 512 thr) ----------------
__global__ __launch_bounds__(512) void k_mexit(const float* __restrict__ Wv, const float* __restrict__ bv,
    const float* __restrict__ We, float* __restrict__ ws){
  const int bu = blockIdx.x >> 2, st = blockIdx.x & 3;
  const int b = bu >> 5, u = bu & 31;
  const int tid = threadIdx.x;
  __shared__ float xs[2][256];
  __shared__ float m2s[128];
  __shared__ float ps[4][128];
  __shared__ float invS[2];
  if(tid < 2){
    const int r = (b*8 + st*2 + tid)*32 + u;
    float v = 0.f;
    #pragma unroll
    for(int k=0;k<8;++k) v += ws[WS_SSUMP + (size_t)r*8 + k];
    invS[tid] = 1.0f / v;
  }
  {
    const int hh = tid >> 8, i = tid & 255;
    const int r = (b*8 + st*2 + hh)*32 + u;
    float s = 0.f;
    #pragma unroll
    for(int vcx=0; vcx<8; ++vcx)
      s += ws[WS_CTXP + ((size_t)vcx*NR_ + r)*IN_ + i];
    xs[hh][i] = s * ws[WS_SCALE + (size_t)bu*2560 + 768 + i];
  }
  __syncthreads();
  {
    const int lo = tid & 127, sp = tid >> 7;
    const int o = st*128 + lo;
    const float4* wv = (const float4*)(Wv + (size_t)o*256 + sp*64);
    const float* xp = &xs[lo>>6][sp*64];
    float acc = 0.f;
    #pragma unroll
    for(int c4=0;c4<16;++c4){
      float4 w = wv[c4];
      acc += w.x*xp[c4*4]+w.y*xp[c4*4+1]+w.z*xp[c4*4+2]+w.w*xp[c4*4+3];
    }
    ps[sp][lo] = acc;
  }
  __syncthreads();
  if(tid < 128){
    const int o = st*128 + tid;
    m2s[tid] = ((ps[0][tid]+ps[1][tid]+ps[2][tid]+ps[3][tid]) * invS[tid>>6] + bv[o])
               * ws[WS_SCALE + (size_t)bu*2560 + 1024 + o];
  }
  __syncthreads();
  {
    const float4* we = (const float4*)(We + (size_t)tid*512 + st*128);
    float acc = 0.f;
    #pragma unroll 8
    for(int c4=0;c4<32;++c4){
      float4 w = we[c4];
      acc += w.x*m2s[c4*4]+w.y*m2s[c4*4+1]+w.z*m2s[c4*4+2]+w.w*m2s[c4*4+3];
    }
    ws[WS_AOP + ((size_t)st*BU_ + bu)*512 + tid] = acc;
  }
}

// ---------------- K4: AO reduce + FFN layernorm + W1 + gelu + scale2 (256 blocks) ----------------
__global__ __launch_bounds__(256) void k_ffn1(const float* __restrict__ be, const float* __restrict__ lsa,
    const float* __restrict__ lg, const float* __restrict__ lb,
    const float* __restrict__ W1, const float* __restrict__ b1, float* __restrict__ ws){
  const int bu = blockIdx.x >> 2, ot = blockIdx.x & 3;
  const int tid = threadIdx.x, wave = tid>>6, lane = tid&63;
  __shared__ float xr[512];
  __shared__ float rsm[4], rqm[4];
  __shared__ float ps[2][128];
  const int s2 = tid*2;
  float2 x2;
  {
    const float* aop = ws + WS_AOP;
    float ax = aop[((size_t)0*BU_+bu)*512+s2] + aop[((size_t)1*BU_+bu)*512+s2]
             + aop[((size_t)2*BU_+bu)*512+s2] + aop[((size_t)3*BU_+bu)*512+s2];
    float ay = aop[((size_t)0*BU_+bu)*512+s2+1] + aop[((size_t)1*BU_+bu)*512+s2+1]
             + aop[((size_t)2*BU_+bu)*512+s2+1] + aop[((size_t)3*BU_+bu)*512+s2+1];
    x2.x = (ax + be[s2])   * lsa[s2];
    x2.y = (ay + be[s2+1]) * lsa[s2+1];
    *(float2*)(ws + WS_AO + (size_t)bu*512 + s2) = x2;
  }
  float s = x2.x+x2.y, q = x2.x*x2.x+x2.y*x2.y;
  s = wsum(s); q = wsum(q);
  if(lane==0){ rsm[wave]=s; rqm[wave]=q; }
  __syncthreads();
  float S=rsm[0]+rsm[1]+rsm[2]+rsm[3], Q=rqm[0]+rqm[1]+rqm[2]+rqm[3];
  float mu = S*(1.0f/512.0f);
  float rv = rsqrtf(Q*(1.0f/512.0f) - mu*mu + 1e-5f);
  const float* scal = ws + WS_SCALE + (size_t)bu*2560;
  xr[s2]   = ((x2.x-mu)*rv*lg[s2]   + lb[s2])   * scal[1536 + s2];
  xr[s2+1] = ((x2.y-mu)*rv*lg[s2+1] + lb[s2+1]) * scal[1536 + s2+1];
  __syncthreads();
  const int o = ot*128 + (tid & 127), sp = tid >> 7;
  const float4* w1 = (const float4*)(W1 + (size_t)o*512 + sp*256);
  const float* xp = xr + sp*256;
  float acc = 0.f;
  #pragma unroll 8
  for(int c4=0;c4<64;++c4){
    float4 w = w1[c4];
    acc += w.x*xp[c4*4]+w.y*xp[c4*4+1]+w.z*xp[c4*4+2]+w.w*xp[c4*4+3];
  }
  ps[sp][tid&127] = acc;
  __syncthreads();
  if(sp==0){
    float hh = ps[0][tid] + ps[1][tid] + b1[o];
    float ge = 0.5f*hh*(1.0f + erff(hh*0.70710678118654752f));
    ws[WS_H2 + (size_t)bu*512 + o] = ge * scal[2048 + o];
  }
}

// ---------------- K5: FFN W2 + residual -> out (256 blocks) ----------------
__global__ __launch_bounds__(256) void k_ffn2(const float* __restrict__ W2, const float* __restrict__ b2,
    const float* __restrict__ lsf, const float* __restrict__ ws, float* __restrict__ out){
  const int bu = blockIdx.x >> 2, st = blockIdx.x & 3;
  const int tid = threadIdx.x;
  const int s = st*128 + (tid & 127), sp = tid >> 7;
  __shared__ float ps[2][128];
  const float4* w2 = (const float4*)(W2 + (size_t)s*512 + sp*256);
  const float* hp = ws + WS_H2 + (size_t)bu*512 + sp*256;
  float acc = 0.f;
  #pragma unroll 8
  for(int c4=0;c4<64;++c4){
    float4 w = w2[c4];
    acc += w.x*hp[c4*4]+w.y*hp[c4*4+1]+w.z*hp[c4*4+2]+w.w*hp[c4*4+3];
  }
  ps[sp][tid&127] = acc;
  __syncthreads();
  if(sp==0)
    out[(size_t)bu*512 + s] = ws[WS_AO + (size_t)bu*512 + s]
                            + (ps[0][tid]+ps[1][tid] + b2[s]) * lsf[s];
}

extern "C" void kernel_launch(void* const* d_in, const int* in_sizes, int n_in,
                              void* d_out, int out_size, void* d_ws, size_t ws_size,
                              hipStream_t stream) {
  (void)in_sizes; (void)n_in; (void)out_size; (void)ws_size;
  const float* rst   = (const float*)d_in[0];
  const float* codes = (const float*)d_in[2];
  const float* snd   = (const float*)d_in[3];
  const float* ln_s_g = (const float*)d_in[4];
  const float* ln_s_b = (const float*)d_in[5];
  const float* ln_r_g = (const float*)d_in[6];
  const float* ln_r_b = (const float*)d_in[7];
  const float* Wq = (const float*)d_in[8];
  const float* bq = (const float*)d_in[9];
  const float* Cq = (const float*)d_in[10];
  const float* Wk = (const float*)d_in[11];
  const float* bk = (const float*)d_in[12];
  const float* Ck = (const float*)d_in[13];
  const float* Wv = (const float*)d_in[14];
  const float* bv = (const float*)d_in[15];
  const float* Cv = (const float*)d_in[16];
  const float* We = (const float*)d_in[17];
  const float* be = (const float*)d_in[18];
  const float* Ce = (const float*)d_in[19];
  const float* lsa = (const float*)d_in[20];
  const float* ln_f_g = (const float*)d_in[21];
  const float* ln_f_b = (const float*)d_in[22];
  const float* W1 = (const float*)d_in[23];
  const float* b1 = (const float*)d_in[24];
  const float* C1 = (const float*)d_in[25];
  const float* W2 = (const float*)d_in[26];
  const float* b2 = (const float*)d_in[27];
  const float* C2 = (const float*)d_in[28];
  const float* lsf = (const float*)d_in[29];
  float* ws  = (float*)d_ws;
  float* out = (float*)d_out;

  k_pre   <<<448, 256, 0, stream>>>(snd, ln_s_g, ln_s_b, codes, Cq, Ck, Cv, Ce, C1, C2, ws);
  k_scctx <<<256, 512, 0, stream>>>(rst, ln_r_g, ln_r_b, Wq, bq, Wk, bk, ws);
  k_mexit <<<256, 512, 0, stream>>>(Wv, bv, We, ws);
  k_ffn1  <<<256, 256, 0, stream>>>(be, lsa, ln_f_g, ln_f_b, W1, b1, ws);
  k_ffn2  <<<256, 256, 0, stream>>>(W2, b2, lsf, ws, out);
}

// Round 8
// 94.180 us; speedup vs baseline: 2.6974x; 1.5816x over previous
//
#include <hip/hip_runtime.h>
#include <math.h>

#define B_ 2
#define U_ 32
#define V_ 2048
#define IN_ 256
#define ST_ 512
#define H_ 8
#define BU_ 64
#define NR_ 512

// ws layout (float offsets)
#define WS_SLN   0u          // [B][V][IN]      1048576
#define WS_SLNT  1048576u    // [B][IN][V]      1048576
#define WS_SCALE 2097152u    // [BU][2560]      163840  (q:0 k:512 v:768 e:1024 f1:1536 f2:2048)
#define WS_T     2260992u    // [NR][IN]        131072
#define WS_CB    2392064u    // [NR]            512
#define WS_SSUMP 2392576u    // [NR][8]         4096
#define WS_CTXP  2396672u    // [8][NR][IN]     1048576
#define WS_AO    3445248u    // [BU][512]       32768
#define WS_H2    3478016u    // [BU][512]       32768
#define WS_AOP   3510784u    // [4][BU][512]    131072

__device__ __forceinline__ float wsum(float v){
  #pragma unroll
  for(int m=32;m>0;m>>=1) v += __shfl_xor(v, m, 64);
  return v;
}

#define FMA4(A, t, S) { A.x += (t)*(S).x; A.y += (t)*(S).y; A.z += (t)*(S).z; A.w += (t)*(S).w; }

// ---------------- K1: fused sender-LN+transpose (blocks 0..127) and scales GEMM (blocks 128..447) ----------------
__global__ __launch_bounds__(256) void k_pre(const float* __restrict__ snd,
    const float* __restrict__ g, const float* __restrict__ bb,
    const float* __restrict__ codes,
    const float* __restrict__ Cq, const float* __restrict__ Ck, const float* __restrict__ Cv,
    const float* __restrict__ Ce, const float* __restrict__ C1, const float* __restrict__ C2,
    float* __restrict__ ws){
  __shared__ float tile[32][261];
  __shared__ float cds[8][256];
  const int tid = threadIdx.x;
  if(blockIdx.x < 128){
    const int wave = tid>>6, lane = tid&63;
    const int rowbase = blockIdx.x * 32;
    const int b = rowbase >> 11, vloc = rowbase & 2047;
    float4 gg  = *(const float4*)(g  + lane*4);
    float4 bbv = *(const float4*)(bb + lane*4);
    for(int it=0; it<8; ++it){
      int rl = it*4 + wave;
      int r  = rowbase + rl;
      float4 x = *(const float4*)(snd + (size_t)r*IN_ + lane*4);
      float s = x.x+x.y+x.z+x.w;
      float q = x.x*x.x+x.y*x.y+x.z*x.z+x.w*x.w;
      s = wsum(s); q = wsum(q);
      float mu = s*(1.0f/256.0f);
      float rv = rsqrtf(q*(1.0f/256.0f) - mu*mu + 1e-5f);
      float4 y;
      y.x = (x.x-mu)*rv*gg.x + bbv.x;
      y.y = (x.y-mu)*rv*gg.y + bbv.y;
      y.z = (x.z-mu)*rv*gg.z + bbv.z;
      y.w = (x.w-mu)*rv*gg.w + bbv.w;
      *(float4*)(ws + WS_SLN + (size_t)r*IN_ + lane*4) = y;
      tile[rl][lane*4+0] = y.x;
      tile[rl][lane*4+1] = y.y;
      tile[rl][lane*4+2] = y.z;
      tile[rl][lane*4+3] = y.w;
    }
    __syncthreads();
    const int vh = tid & 31;
    const int ibase = (tid >> 5);
    for(int it=0; it<32; ++it){
      int i = it*8 + ibase;
      ws[WS_SLNT + ((size_t)b*IN_ + i)*V_ + vloc + vh] = tile[vh][i];
    }
  } else {
    const int idx = blockIdx.x - 128;
    const int cg = idx % 40, bg = idx / 40;
    #pragma unroll
    for(int j=0;j<8;++j){
      int fi = j*256 + tid;
      cds[fi>>8][fi&255] = codes[(size_t)(bg*8)*256 + fi];
    }
    __syncthreads();
    const int q = tid & 3;
    const int col = cg*64 + (tid >> 2);
    const float* Cp; int loc;
    if(col < 512){ Cp = Cq; loc = col; }
    else if(col < 768){ Cp = Ck; loc = col - 512; }
    else if(col < 1024){ Cp = Cv; loc = col - 768; }
    else if(col < 1536){ Cp = Ce; loc = col - 1024; }
    else if(col < 2048){ Cp = C1; loc = col - 1536; }
    else { Cp = C2; loc = col - 2048; }
    const float4* wrow = (const float4*)(Cp + (size_t)loc*256 + q*64);
    float acc[8] = {0,0,0,0,0,0,0,0};
    #pragma unroll 4
    for(int i=0;i<16;++i){
      float4 w = wrow[i];
      #pragma unroll
      for(int k=0;k<8;++k){
        const float4 c = *(const float4*)(&cds[k][q*64 + i*4]);
        acc[k] += w.x*c.x + w.y*c.y + w.z*c.z + w.w*c.w;
      }
    }
    #pragma unroll
    for(int k=0;k<8;++k){
      acc[k] += __shfl_xor(acc[k], 1, 64);
      acc[k] += __shfl_xor(acc[k], 2, 64);
    }
    ws[WS_SCALE + (size_t)(bg*8 + q)*2560 + col]     = 1.0f + acc[q];
    ws[WS_SCALE + (size_t)(bg*8 + q + 4)*2560 + col] = 1.0f + acc[q+4];
  }
}

// ---------------- K2: receiver LN + q head-slice + t_k + cb (512 blocks = bu x h) ----------------
__global__ __launch_bounds__(256) void k_qt(const float* __restrict__ rst,
    const float* __restrict__ lg, const float* __restrict__ lb,
    const float* __restrict__ Wq, const float* __restrict__ bq,
    const float* __restrict__ Wk, const float* __restrict__ bk,
    float* __restrict__ ws){
  const int bu = blockIdx.x >> 3, h = blockIdx.x & 7;
  const int b = bu >> 5, u = bu & 31;
  const int r = (b*8 + h)*32 + u;
  const int tid = threadIdx.x, wave = tid>>6, lane = tid&63;
  __shared__ float xm[512];
  __shared__ float qv[64];
  __shared__ float red[4][65];
  __shared__ float rsm[4], rqm[4];
  float2 x2 = *(const float2*)(rst + (size_t)bu*512 + tid*2);
  float s = x2.x + x2.y, q = x2.x*x2.x + x2.y*x2.y;
  s = wsum(s); q = wsum(q);
  if(lane==0){ rsm[wave] = s; rqm[wave] = q; }
  __syncthreads();
  float S = rsm[0]+rsm[1]+rsm[2]+rsm[3];
  float Q = rqm[0]+rqm[1]+rqm[2]+rqm[3];
  float mu = S*(1.0f/512.0f);
  float rv = rsqrtf(Q*(1.0f/512.0f) - mu*mu + 1e-5f);
  const float* scal = ws + WS_SCALE + (size_t)bu*2560;
  xm[tid*2]   = ((x2.x-mu)*rv*lg[tid*2]   + lb[tid*2])   * scal[tid*2];
  xm[tid*2+1] = ((x2.y-mu)*rv*lg[tid*2+1] + lb[tid*2+1]) * scal[tid*2+1];
  __syncthreads();
  {
    const int o = tid & 63, sp = tid >> 6;
    const float4* wq = (const float4*)(Wq + (size_t)(h*64 + o)*512 + sp*128);
    const float* xp = xm + sp*128;
    float acc = 0.f;
    #pragma unroll 8
    for(int c4=0;c4<32;++c4){
      float4 w = wq[c4];
      acc += w.x*xp[c4*4] + w.y*xp[c4*4+1] + w.z*xp[c4*4+2] + w.w*xp[c4*4+3];
    }
    red[sp][o] = acc;
  }
  __syncthreads();
  if(tid < 64)
    qv[tid] = red[0][tid]+red[1][tid]+red[2][tid]+red[3][tid] + bq[h*64+tid];
  __syncthreads();
  if(tid < 64){
    float p = qv[tid] * bk[h*64+tid];
    p = wsum(p);
    if(tid==0) ws[WS_CB + r] = p;
  }
  {
    float acc = 0.f;
    #pragma unroll 4
    for(int d=0; d<64; ++d)
      acc += qv[d] * Wk[(size_t)(h*64+d)*256 + tid];
    ws[WS_T + (size_t)r*256 + tid] = acc * scal[512 + tid];
  }
}

// ---------------- K3: fused scores->exp->ctx v4. 512 blocks x 512 thr, 8 rows/block, 2 blocks/CU ----------------
// block: 8 rows x 256 v. waves: wr(0..1) row-quad x wk(0..3) K-quarter. LDS 40KB.
__global__ __launch_bounds__(512) void k_scctx(const float* __restrict__ Tm, float* __restrict__ ws){
  const int rg = blockIdx.x >> 3, vc = blockIdx.x & 7;   // 64 rowgroups(8) x 8 vchunks(256)
  const int r0 = rg * 8;
  const int b  = rg >> 5;
  const int v0 = vc * 256;
  const int tid = threadIdx.x, lane = tid & 63;
  const int w  = __builtin_amdgcn_readfirstlane(tid >> 6);
  const int wr = w & 1, wk = w >> 1;
  const int rw4 = wr * 4;
  const int i0 = lane * 4;
  const int srow = tid >> 6;
  const int sf   = (tid & 63) * 4;

  __shared__ float P[8][256];      // 8KB
  __shared__ float stg[32][256];   // 32KB

  float4 a0={0,0,0,0},a1={0,0,0,0},a2={0,0,0,0},a3={0,0,0,0};
  const float* Trow = Tm + (size_t)(r0 + rw4)*256;   // wave-uniform base

  // ================= phase 1: scores = T x sT =================
  const float* p1base = ws + WS_SLNT + (size_t)b*IN_*V_ + v0;
  float4 g0,g1,g2,g3;
  g0 = *(const float4*)(p1base + (size_t)(srow    )*V_ + sf);
  g1 = *(const float4*)(p1base + (size_t)(srow+ 8)*V_ + sf);
  g2 = *(const float4*)(p1base + (size_t)(srow+16)*V_ + sf);
  g3 = *(const float4*)(p1base + (size_t)(srow+24)*V_ + sf);
  for(int s=0; s<8; ++s){
    __syncthreads();
    *(float4*)&stg[srow   ][sf] = g0;
    *(float4*)&stg[srow+ 8][sf] = g1;
    *(float4*)&stg[srow+16][sf] = g2;
    *(float4*)&stg[srow+24][sf] = g3;
    if(s < 7){
      const float* nb = p1base + (size_t)(s+1)*32*V_;
      g0 = *(const float4*)(nb + (size_t)(srow    )*V_ + sf);
      g1 = *(const float4*)(nb + (size_t)(srow+ 8)*V_ + sf);
      g2 = *(const float4*)(nb + (size_t)(srow+16)*V_ + sf);
      g3 = *(const float4*)(nb + (size_t)(srow+24)*V_ + sf);
    }
    const int kgA = s*32 + wk*8;       // uniform
    float4 tA[4], tB[4];
    #pragma unroll
    for(int j=0;j<4;++j) tA[j] = *(const float4*)(Trow + (size_t)j*256 + kgA);
    __syncthreads();
    #pragma unroll
    for(int j=0;j<4;++j) tB[j] = *(const float4*)(Trow + (size_t)j*256 + kgA + 4);
    {
      const int kl = wk*8;
      float4 s0 = *(const float4*)&stg[kl+0][i0];
      float4 s1 = *(const float4*)&stg[kl+1][i0];
      float4 s2 = *(const float4*)&stg[kl+2][i0];
      float4 s3 = *(const float4*)&stg[kl+3][i0];
      FMA4(a0,tA[0].x,s0) FMA4(a0,tA[0].y,s1) FMA4(a0,tA[0].z,s2) FMA4(a0,tA[0].w,s3)
      FMA4(a1,tA[1].x,s0) FMA4(a1,tA[1].y,s1) FMA4(a1,tA[1].z,s2) FMA4(a1,tA[1].w,s3)
      FMA4(a2,tA[2].x,s0) FMA4(a2,tA[2].y,s1) FMA4(a2,tA[2].z,s2) FMA4(a2,tA[2].w,s3)
      FMA4(a3,tA[3].x,s0) FMA4(a3,tA[3].y,s1) FMA4(a3,tA[3].z,s2) FMA4(a3,tA[3].w,s3)
    }
    {
      const int kl = wk*8 + 4;
      float4 s0 = *(const float4*)&stg[kl+0][i0];
      float4 s1 = *(const float4*)&stg[kl+1][i0];
      float4 s2 = *(const float4*)&stg[kl+2][i0];
      float4 s3 = *(const float4*)&stg[kl+3][i0];
      FMA4(a0,tB[0].x,s0) FMA4(a0,tB[0].y,s1) FMA4(a0,tB[0].z,s2) FMA4(a0,tB[0].w,s3)
      FMA4(a1,tB[1].x,s0) FMA4(a1,tB[1].y,s1) FMA4(a1,tB[1].z,s2) FMA4(a1,tB[1].w,s3)
      FMA4(a2,tB[2].x,s0) FMA4(a2,tB[2].y,s1) FMA4(a2,tB[2].z,s2) FMA4(a2,tB[2].w,s3)
      FMA4(a3,tB[3].x,s0) FMA4(a3,tB[3].y,s1) FMA4(a3,tB[3].z,s2) FMA4(a3,tB[3].w,s3)
    }
  }
  // ---- reduce 4 K-quarters: wk0->P, wk1->stg[0:8), wk2->stg[8:16), wk3 finishes ----
  __syncthreads();
  if(wk == 0){
    *(float4*)&P[rw4+0][i0]=a0; *(float4*)&P[rw4+1][i0]=a1;
    *(float4*)&P[rw4+2][i0]=a2; *(float4*)&P[rw4+3][i0]=a3;
  } else if(wk == 1){
    *(float4*)&stg[rw4+0][i0]=a0; *(float4*)&stg[rw4+1][i0]=a1;
    *(float4*)&stg[rw4+2][i0]=a2; *(float4*)&stg[rw4+3][i0]=a3;
  } else if(wk == 2){
    *(float4*)&stg[8+rw4+0][i0]=a0; *(float4*)&stg[8+rw4+1][i0]=a1;
    *(float4*)&stg[8+rw4+2][i0]=a2; *(float4*)&stg[8+rw4+3][i0]=a3;
  }
  __syncthreads();
  if(wk == 3){
    float4 av[4] = {a0,a1,a2,a3};
    #pragma unroll
    for(int j=0;j<4;++j){
      const int r = r0 + rw4 + j;
      const float cb = ws[WS_CB + r];
      float4 q0 = *(const float4*)&P[rw4+j][i0];
      float4 q1 = *(const float4*)&stg[rw4+j][i0];
      float4 q2 = *(const float4*)&stg[8+rw4+j][i0];
      float4 e;
      e.x = __expf((av[j].x+q0.x+q1.x+q2.x+cb)*0.125f);
      e.y = __expf((av[j].y+q0.y+q1.y+q2.y+cb)*0.125f);
      e.z = __expf((av[j].z+q0.z+q1.z+q2.z+cb)*0.125f);
      e.w = __expf((av[j].w+q0.w+q1.w+q2.w+cb)*0.125f);
      *(float4*)&P[rw4+j][i0] = e;
      float ss = wsum(e.x+e.y+e.z+e.w);
      if(lane==0) ws[WS_SSUMP + (size_t)r*8 + vc] = ss;
    }
  }

  // ================= phase 2: ctx = P x SL =================
  a0=make_float4(0,0,0,0); a1=a0; a2=a0; a3=a0;
  const float* p2base = ws + WS_SLN + ((size_t)b*V_ + v0)*IN_;
  g0 = *(const float4*)(p2base + (size_t)(srow    )*IN_ + sf);
  g1 = *(const float4*)(p2base + (size_t)(srow+ 8)*IN_ + sf);
  g2 = *(const float4*)(p2base + (size_t)(srow+16)*IN_ + sf);
  g3 = *(const float4*)(p2base + (size_t)(srow+24)*IN_ + sf);
  for(int sv=0; sv<8; ++sv){
    __syncthreads();     // first pass also fences P exp-writes + partial reads
    *(float4*)&stg[srow   ][sf] = g0;
    *(float4*)&stg[srow+ 8][sf] = g1;
    *(float4*)&stg[srow+16][sf] = g2;
    *(float4*)&stg[srow+24][sf] = g3;
    if(sv < 7){
      const float* nb = p2base + (size_t)(sv+1)*32*IN_;
      g0 = *(const float4*)(nb + (size_t)(srow    )*IN_ + sf);
      g1 = *(const float4*)(nb + (size_t)(srow+ 8)*IN_ + sf);
      g2 = *(const float4*)(nb + (size_t)(srow+16)*IN_ + sf);
      g3 = *(const float4*)(nb + (size_t)(srow+24)*IN_ + sf);
    }
    __syncthreads();
    #pragma unroll
    for(int half=0; half<2; ++half){
      const int vl = wk*8 + half*4, vg = sv*32 + vl;
      float4 p0_ = *(const float4*)&P[rw4+0][vg];
      float4 p1_ = *(const float4*)&P[rw4+1][vg];
      float4 p2_ = *(const float4*)&P[rw4+2][vg];
      float4 p3_ = *(const float4*)&P[rw4+3][vg];
      float4 s0 = *(const float4*)&stg[vl+0][i0];
      float4 s1 = *(const float4*)&stg[vl+1][i0];
      float4 s2 = *(const float4*)&stg[vl+2][i0];
      float4 s3 = *(const float4*)&stg[vl+3][i0];
      FMA4(a0,p0_.x,s0) FMA4(a0,p0_.y,s1) FMA4(a0,p0_.z,s2) FMA4(a0,p0_.w,s3)
      FMA4(a1,p1_.x,s0) FMA4(a1,p1_.y,s1) FMA4(a1,p1_.z,s2) FMA4(a1,p1_.w,s3)
      FMA4(a2,p2_.x,s0) FMA4(a2,p2_.y,s1) FMA4(a2,p2_.z,s2) FMA4(a2,p2_.w,s3)
      FMA4(a3,p3_.x,s0) FMA4(a3,p3_.y,s1) FMA4(a3,p3_.z,s2) FMA4(a3,p3_.w,s3)
    }
  }
  // ---- reduce 4 v-quarters and store CTXP ----
  __syncthreads();
  if(wk == 0){
    *(float4*)&P[rw4+0][i0]=a0; *(float4*)&P[rw4+1][i0]=a1;
    *(float4*)&P[rw4+2][i0]=a2; *(float4*)&P[rw4+3][i0]=a3;
  } else if(wk == 1){
    *(float4*)&stg[rw4+0][i0]=a0; *(float4*)&stg[rw4+1][i0]=a1;
    *(float4*)&stg[rw4+2][i0]=a2; *(float4*)&stg[rw4+3][i0]=a3;
  } else if(wk == 2){
    *(float4*)&stg[8+rw4+0][i0]=a0; *(float4*)&stg[8+rw4+1][i0]=a1;
    *(float4*)&stg[8+rw4+2][i0]=a2; *(float4*)&stg[8+rw4+3][i0]=a3;
  }
  __syncthreads();
  if(wk == 3){
    float4 av[4] = {a0,a1,a2,a3};
    #pragma unroll
    for(int j=0;j<4;++j){
      const int r = r0 + rw4 + j;
      float4 q0 = *(const float4*)&P[rw4+j][i0];
      float4 q1 = *(const float4*)&stg[rw4+j][i0];
      float4 q2 = *(const float4*)&stg[8+rw4+j][i0];
      float4 d;
      d.x = av[j].x+q0.x+q1.x+q2.x;
      d.y = av[j].y+q0.y+q1.y+q2.y;
      d.z = av[j].z+q0.z+q1.z+q2.z;
      d.w = av[j].w+q0.w+q1.w+q2.w;
      *(float4*)(ws + WS_CTXP + ((size_t)vc*NR_ + r)*IN_ + i0) = d;
    }
  }
}

// ---------------- K4: msg+exit, column-split We -> AO partials (256 blocks = bu x st, 512 thr) ----------------
__global__ __launch_bounds__(512) void k_mexit(const float* __restrict__ Wv, const float* __restrict__ bv,
    const float* __restrict__ We, float* __restrict__ ws){
  const int bu = blockIdx.x >> 2, st = blockIdx.x & 3;
  const int b = bu >> 5, u = bu & 31;
  const int tid = threadIdx.x;
  __shared__ float xs[2][256];
  __shared__ float m2s[128];
  __shared__ float ps[4][128];
  __shared__ float invS[2];
  if(tid < 2){
    const int r = (b*8 + st*2 + tid)*32 + u;
    float v = 0.f;
    #pragma unroll
    for(int k=0;k<8;++k) v += ws[WS_SSUMP + (size_t)r*8 + k];
    invS[tid] = 1.0f / v;
  }
  {
    const int hh = tid >> 8, i = tid & 255;
    const int r = (b*8 + st*2 + hh)*32 + u;
    float s = 0.f;
    #pragma unroll
    for(int vcx=0; vcx<8; ++vcx)
      s += ws[WS_CTXP + ((size_t)vcx*NR_ + r)*IN_ + i];
    xs[hh][i] = s * ws[WS_SCALE + (size_t)bu*2560 + 768 + i];
  }
  __syncthreads();
  {
    const int lo = tid & 127, sp = tid >> 7;
    const int o = st*128 + lo;
    const float4* wv = (const float4*)(Wv + (size_t)o*256 + sp*64);
    const float* xp = &xs[lo>>6][sp*64];
    float acc = 0.f;
    #pragma unroll
    for(int c4=0;c4<16;++c4){
      float4 w = wv[c4];
      acc += w.x*xp[c4*4]+w.y*xp[c4*4+1]+w.z*xp[c4*4+2]+w.w*xp[c4*4+3];
    }
    ps[sp][lo] = acc;
  }
  __syncthreads();
  if(tid < 128){
    const int o = st*128 + tid;
    m2s[tid] = ((ps[0][tid]+ps[1][tid]+ps[2][tid]+ps[3][tid]) * invS[tid>>6] + bv[o])
               * ws[WS_SCALE + (size_t)bu*2560 + 1024 + o];
  }
  __syncthreads();
  {
    const float4* we = (const float4*)(We + (size_t)tid*512 + st*128);
    float acc = 0.f;
    #pragma unroll 8
    for(int c4=0;c4<32;++c4){
      float4 w = we[c4];
      acc += w.x*m2s[c4*4]+w.y*m2s[c4*4+1]+w.z*m2s[c4*4+2]+w.w*m2s[c4*4+3];
    }
    ws[WS_AOP + ((size_t)st*BU_ + bu)*512 + tid] = acc;
  }
}

// ---------------- K5: AO reduce + FFN layernorm + W1 + gelu + scale2 (256 blocks) ----------------
__global__ __launch_bounds__(256) void k_ffn1(const float* __restrict__ be, const float* __restrict__ lsa,
    const float* __restrict__ lg, const float* __restrict__ lb,
    const float* __restrict__ W1, const float* __restrict__ b1, float* __restrict__ ws){
  const int bu = blockIdx.x >> 2, ot = blockIdx.x & 3;
  const int tid = threadIdx.x, wave = tid>>6, lane = tid&63;
  __shared__ float xr[512];
  __shared__ float rsm[4], rqm[4];
  __shared__ float ps[2][128];
  const int s2 = tid*2;
  float2 x2;
  {
    const float* aop = ws + WS_AOP;
    float ax = aop[((size_t)0*BU_+bu)*512+s2] + aop[((size_t)1*BU_+bu)*512+s2]
             + aop[((size_t)2*BU_+bu)*512+s2] + aop[((size_t)3*BU_+bu)*512+s2];
    float ay = aop[((size_t)0*BU_+bu)*512+s2+1] + aop[((size_t)1*BU_+bu)*512+s2+1]
             + aop[((size_t)2*BU_+bu)*512+s2+1] + aop[((size_t)3*BU_+bu)*512+s2+1];
    x2.x = (ax + be[s2])   * lsa[s2];
    x2.y = (ay + be[s2+1]) * lsa[s2+1];
    *(float2*)(ws + WS_AO + (size_t)bu*512 + s2) = x2;
  }
  float s = x2.x+x2.y, q = x2.x*x2.x+x2.y*x2.y;
  s = wsum(s); q = wsum(q);
  if(lane==0){ rsm[wave]=s; rqm[wave]=q; }
  __syncthreads();
  float S=rsm[0]+rsm[1]+rsm[2]+rsm[3], Q=rqm[0]+rqm[1]+rqm[2]+rqm[3];
  float mu = S*(1.0f/512.0f);
  float rv = rsqrtf(Q*(1.0f/512.0f) - mu*mu + 1e-5f);
  const float* scal = ws + WS_SCALE + (size_t)bu*2560;
  xr[s2]   = ((x2.x-mu)*rv*lg[s2]   + lb[s2])   * scal[1536 + s2];
  xr[s2+1] = ((x2.y-mu)*rv*lg[s2+1] + lb[s2+1]) * scal[1536 + s2+1];
  __syncthreads();
  const int o = ot*128 + (tid & 127), sp = tid >> 7;
  const float4* w1 = (const float4*)(W1 + (size_t)o*512 + sp*256);
  const float* xp = xr + sp*256;
  float acc = 0.f;
  #pragma unroll 8
  for(int c4=0;c4<64;++c4){
    float4 w = w1[c4];
    acc += w.x*xp[c4*4]+w.y*xp[c4*4+1]+w.z*xp[c4*4+2]+w.w*xp[c4*4+3];
  }
  ps[sp][tid&127] = acc;
  __syncthreads();
  if(sp==0){
    float hh = ps[0][tid] + ps[1][tid] + b1[o];
    float ge = 0.5f*hh*(1.0f + erff(hh*0.70710678118654752f));
    ws[WS_H2 + (size_t)bu*512 + o] = ge * scal[2048 + o];
  }
}

// ---------------- K6: FFN W2 + residual -> out (256 blocks) ----------------
__global__ __launch_bounds__(256) void k_ffn2(const float* __restrict__ W2, const float* __restrict__ b2,
    const float* __restrict__ lsf, const float* __restrict__ ws, float* __restrict__ out){
  const int bu = blockIdx.x >> 2, st = blockIdx.x & 3;
  const int tid = threadIdx.x;
  const int s = st*128 + (tid & 127), sp = tid >> 7;
  __shared__ float ps[2][128];
  const float4* w2 = (const float4*)(W2 + (size_t)s*512 + sp*256);
  const float* hp = ws + WS_H2 + (size_t)bu*512 + sp*256;
  float acc = 0.f;
  #pragma unroll 8
  for(int c4=0;c4<64;++c4){
    float4 w = w2[c4];
    acc += w.x*hp[c4*4]+w.y*hp[c4*4+1]+w.z*hp[c4*4+2]+w.w*hp[c4*4+3];
  }
  ps[sp][tid&127] = acc;
  __syncthreads();
  if(sp==0)
    out[(size_t)bu*512 + s] = ws[WS_AO + (size_t)bu*512 + s]
                            + (ps[0][tid]+ps[1][tid] + b2[s]) * lsf[s];
}

extern "C" void kernel_launch(void* const* d_in, const int* in_sizes, int n_in,
                              void* d_out, int out_size, void* d_ws, size_t ws_size,
                              hipStream_t stream) {
  (void)in_sizes; (void)n_in; (void)out_size; (void)ws_size;
  const float* rst   = (const float*)d_in[0];
  const float* codes = (const float*)d_in[2];
  const float* snd   = (const float*)d_in[3];
  const float* ln_s_g = (const float*)d_in[4];
  const float* ln_s_b = (const float*)d_in[5];
  const float* ln_r_g = (const float*)d_in[6];
  const float* ln_r_b = (const float*)d_in[7];
  const float* Wq = (const float*)d_in[8];
  const float* bq = (const float*)d_in[9];
  const float* Cq = (const float*)d_in[10];
  const float* Wk = (const float*)d_in[11];
  const float* bk = (const float*)d_in[12];
  const float* Ck = (const float*)d_in[13];
  const float* Wv = (const float*)d_in[14];
  const float* bv = (const float*)d_in[15];
  const float* Cv = (const float*)d_in[16];
  const float* We = (const float*)d_in[17];
  const float* be = (const float*)d_in[18];
  const float* Ce = (const float*)d_in[19];
  const float* lsa = (const float*)d_in[20];
  const float* ln_f_g = (const float*)d_in[21];
  const float* ln_f_b = (const float*)d_in[22];
  const float* W1 = (const float*)d_in[23];
  const float* b1 = (const float*)d_in[24];
  const float* C1 = (const float*)d_in[25];
  const float* W2 = (const float*)d_in[26];
  const float* b2 = (const float*)d_in[27];
  const float* C2 = (const float*)d_in[28];
  const float* lsf = (const float*)d_in[29];
  float* ws  = (float*)d_ws;
  float* out = (float*)d_out;

  k_pre   <<<448, 256, 0, stream>>>(snd, ln_s_g, ln_s_b, codes, Cq, Ck, Cv, Ce, C1, C2, ws);
  k_qt    <<<512, 256, 0, stream>>>(rst, ln_r_g, ln_r_b, Wq, bq, Wk, bk, ws);
  k_scctx <<<512, 512, 0, stream>>>((const float*)(ws + WS_T), ws);
  k_mexit <<<256, 512, 0, stream>>>(Wv, bv, We, ws);
  k_ffn1  <<<256, 256, 0, stream>>>(be, lsa, ln_f_g, ln_f_b, W1, b1, ws);
  k_ffn2  <<<256, 256, 0, stream>>>(W2, b2, lsf, ws, out);
}